// Round 1
// baseline (1838.251 us; speedup 1.0000x reference)
//
#include <hip/hip_runtime.h>
#include <hip/hip_bf16.h>

#define B_SZ   1024
#define T_SZ   64
#define D_IN   1662
#define M_SZ   (B_SZ * T_SZ)   // 65536

// ---------------------------------------------------------------------------
// GEMM: out[M,G] = A[M,K] @ W[G,K]^T + (bi[g] + bh[g])
// 64x64 tile, BK=16, 256 threads, 4x4 micro-tile.
// ---------------------------------------------------------------------------
__global__ __launch_bounds__(256) void gemm_bias(
    const float* __restrict__ A, const float* __restrict__ W,
    const float* __restrict__ bi, const float* __restrict__ bh,
    float* __restrict__ out, int M, int K, int G)
{
    __shared__ __align__(16) float As[16][68];
    __shared__ __align__(16) float Ws[16][68];

    const int tid = threadIdx.x;
    const int tx = tid & 15, ty = tid >> 4;
    const int m0 = blockIdx.y * 64, g0 = blockIdx.x * 64;
    const int lrow = tid >> 2;          // 0..63
    const int lk   = (tid & 3) * 4;     // 0,4,8,12

    float acc[4][4] = {{0.f}};

    const float* Ap = A + (size_t)(m0 + lrow) * K;
    const float* Wp = W + (size_t)(g0 + lrow) * K;

    for (int k0 = 0; k0 < K; k0 += 16) {
        const int kk = k0 + lk;
        float a0 = (kk + 0 < K) ? Ap[kk + 0] : 0.f;
        float a1 = (kk + 1 < K) ? Ap[kk + 1] : 0.f;
        float a2 = (kk + 2 < K) ? Ap[kk + 2] : 0.f;
        float a3 = (kk + 3 < K) ? Ap[kk + 3] : 0.f;
        float w0 = (kk + 0 < K) ? Wp[kk + 0] : 0.f;
        float w1 = (kk + 1 < K) ? Wp[kk + 1] : 0.f;
        float w2 = (kk + 2 < K) ? Wp[kk + 2] : 0.f;
        float w3 = (kk + 3 < K) ? Wp[kk + 3] : 0.f;

        __syncthreads();
        As[lk + 0][lrow] = a0; As[lk + 1][lrow] = a1;
        As[lk + 2][lrow] = a2; As[lk + 3][lrow] = a3;
        Ws[lk + 0][lrow] = w0; Ws[lk + 1][lrow] = w1;
        Ws[lk + 2][lrow] = w2; Ws[lk + 3][lrow] = w3;
        __syncthreads();

        #pragma unroll
        for (int k = 0; k < 16; ++k) {
            float4 a4 = *(const float4*)&As[k][ty * 4];
            float4 w4 = *(const float4*)&Ws[k][tx * 4];
            acc[0][0] = fmaf(a4.x, w4.x, acc[0][0]);
            acc[0][1] = fmaf(a4.x, w4.y, acc[0][1]);
            acc[0][2] = fmaf(a4.x, w4.z, acc[0][2]);
            acc[0][3] = fmaf(a4.x, w4.w, acc[0][3]);
            acc[1][0] = fmaf(a4.y, w4.x, acc[1][0]);
            acc[1][1] = fmaf(a4.y, w4.y, acc[1][1]);
            acc[1][2] = fmaf(a4.y, w4.z, acc[1][2]);
            acc[1][3] = fmaf(a4.y, w4.w, acc[1][3]);
            acc[2][0] = fmaf(a4.z, w4.x, acc[2][0]);
            acc[2][1] = fmaf(a4.z, w4.y, acc[2][1]);
            acc[2][2] = fmaf(a4.z, w4.z, acc[2][2]);
            acc[2][3] = fmaf(a4.z, w4.w, acc[2][3]);
            acc[3][0] = fmaf(a4.w, w4.x, acc[3][0]);
            acc[3][1] = fmaf(a4.w, w4.y, acc[3][1]);
            acc[3][2] = fmaf(a4.w, w4.z, acc[3][2]);
            acc[3][3] = fmaf(a4.w, w4.w, acc[3][3]);
        }
    }

    const int g = g0 + tx * 4;
    float4 bv;
    bv.x = bi[g + 0] + bh[g + 0];
    bv.y = bi[g + 1] + bh[g + 1];
    bv.z = bi[g + 2] + bh[g + 2];
    bv.w = bi[g + 3] + bh[g + 3];
    #pragma unroll
    for (int i = 0; i < 4; ++i) {
        const int m = m0 + ty * 4 + i;
        float4 o;
        o.x = acc[i][0] + bv.x;
        o.y = acc[i][1] + bv.y;
        o.z = acc[i][2] + bv.z;
        o.w = acc[i][3] + bv.w;
        *(float4*)&out[(size_t)m * G + g] = o;
    }
}

// ---------------------------------------------------------------------------
// LSTM recurrence. One block handles RB batch rows for all T steps.
// 4H threads; thread j owns gate column j (w_hh row j in registers).
// Gate order (PyTorch): i, f, g, o.
// ---------------------------------------------------------------------------
__device__ __forceinline__ float sigmoid_f(float x) {
    return 1.0f / (1.0f + __expf(-x));
}
__device__ __forceinline__ float tanh_f(float x) {
    float a = fabsf(x);
    float e = __expf(2.0f * a);       // inf for large a -> r = 1
    float r = 1.0f - 2.0f / (e + 1.0f);
    return copysignf(r, x);
}

template<int H, int RB>
__global__ __launch_bounds__(4 * H) void lstm_rec(
    const float* __restrict__ xg,   // [B, T, 4H]  (input proj + both biases)
    const float* __restrict__ whh,  // [4H, H]
    float* __restrict__ hout,       // [B, T, H]
    int Tn)
{
    constexpr int G = 4 * H;
    const int tid = threadIdx.x;           // 0..G-1
    const int r0  = blockIdx.x * RB;

    __shared__ __align__(16) float h_lds[RB][H];
    __shared__ __align__(16) float g_lds[RB][G];

    // w_hh row for this thread's gate column (contiguous -> float4 loads)
    float wreg[H];
    {
        const float4* wp = (const float4*)(whh + (size_t)tid * H);
        #pragma unroll
        for (int q = 0; q < H / 4; ++q) {
            float4 v = wp[q];
            wreg[4 * q + 0] = v.x; wreg[4 * q + 1] = v.y;
            wreg[4 * q + 2] = v.z; wreg[4 * q + 3] = v.w;
        }
    }

    // cell-state ownership: RB*H == G, one item per thread
    const int cr = tid / H, cu = tid % H;
    float c = 0.f;
    h_lds[cr][cu] = 0.f;
    __syncthreads();

    for (int t = 0; t < Tn; ++t) {
        // Phase A: gates = xg[:,t,:] + h @ whh^T  (this thread: column tid)
        float acc[RB];
        #pragma unroll
        for (int r = 0; r < RB; ++r)
            acc[r] = xg[((size_t)(r0 + r) * Tn + t) * G + tid];
        #pragma unroll
        for (int r = 0; r < RB; ++r) {
            #pragma unroll
            for (int q = 0; q < H / 4; ++q) {
                float4 hv = *(const float4*)&h_lds[r][4 * q];
                acc[r] = fmaf(hv.x, wreg[4 * q + 0], acc[r]);
                acc[r] = fmaf(hv.y, wreg[4 * q + 1], acc[r]);
                acc[r] = fmaf(hv.z, wreg[4 * q + 2], acc[r]);
                acc[r] = fmaf(hv.w, wreg[4 * q + 3], acc[r]);
            }
        }
        #pragma unroll
        for (int r = 0; r < RB; ++r) g_lds[r][tid] = acc[r];
        __syncthreads();

        // Phase B: cell update for item (cr, cu)
        float gi = g_lds[cr][cu];
        float gf = g_lds[cr][H + cu];
        float gg = g_lds[cr][2 * H + cu];
        float go = g_lds[cr][3 * H + cu];
        float iv = sigmoid_f(gi);
        float fv = sigmoid_f(gf);
        float gv = tanh_f(gg);
        float ov = sigmoid_f(go);
        c = fmaf(fv, c, iv * gv);
        float h = ov * tanh_f(c);
        h_lds[cr][cu] = h;
        hout[((size_t)(r0 + cr) * Tn + t) * H + cu] = h;
        __syncthreads();
    }
}

// ---------------------------------------------------------------------------
// FC head: h3[:, T-1, :64] -> fc1(64) relu -> fc2(32) relu -> fc3(3) -> softmax
// 16 rows per block, 256 threads.
// ---------------------------------------------------------------------------
__global__ __launch_bounds__(256) void head_kernel(
    const float* __restrict__ h3,   // [B, T, 64]
    const float* __restrict__ w1, const float* __restrict__ b1,  // [64,64],[64]
    const float* __restrict__ w2, const float* __restrict__ b2,  // [32,64],[32]
    const float* __restrict__ w3, const float* __restrict__ b3,  // [3,32],[3]
    float* __restrict__ out, int Tn)
{
    __shared__ float W1[64][64];
    __shared__ float W2[32][64];
    __shared__ float W3[3][32];
    __shared__ float hin[16][64];
    __shared__ float a1[16][64];
    __shared__ float a2[16][32];
    __shared__ float lg[16][3];

    const int tid = threadIdx.x;
    const int r0 = blockIdx.x * 16;

    for (int i = tid; i < 64 * 64; i += 256) W1[i >> 6][i & 63] = w1[i];
    for (int i = tid; i < 32 * 64; i += 256) W2[i >> 6][i & 63] = w2[i];
    for (int i = tid; i < 3 * 32; i += 256) W3[i >> 5][i & 31] = w3[i];
    for (int i = tid; i < 16 * 64; i += 256) {
        int r = i >> 6, u = i & 63;
        hin[r][u] = h3[((size_t)(r0 + r) * Tn + (Tn - 1)) * 64 + u];
    }
    __syncthreads();

    for (int i = tid; i < 16 * 64; i += 256) {
        int r = i >> 6, j = i & 63;
        float s = b1[j];
        #pragma unroll
        for (int k = 0; k < 64; ++k) s = fmaf(hin[r][k], W1[j][k], s);
        a1[r][j] = fmaxf(s, 0.f);
    }
    __syncthreads();

    for (int i = tid; i < 16 * 32; i += 256) {
        int r = i >> 5, j = i & 31;
        float s = b2[j];
        #pragma unroll
        for (int k = 0; k < 64; ++k) s = fmaf(a1[r][k], W2[j][k], s);
        a2[r][j] = fmaxf(s, 0.f);
    }
    __syncthreads();

    for (int i = tid; i < 16 * 3; i += 256) {
        int r = i / 3, j = i % 3;
        float s = b3[j];
        #pragma unroll
        for (int k = 0; k < 32; ++k) s = fmaf(a2[r][k], W3[j][k], s);
        lg[r][j] = s;
    }
    __syncthreads();

    if (tid < 16) {
        float l0 = lg[tid][0], l1 = lg[tid][1], l2 = lg[tid][2];
        float m = fmaxf(l0, fmaxf(l1, l2));
        float e0 = __expf(l0 - m), e1 = __expf(l1 - m), e2 = __expf(l2 - m);
        float inv = 1.0f / (e0 + e1 + e2);
        out[(size_t)(r0 + tid) * 3 + 0] = e0 * inv;
        out[(size_t)(r0 + tid) * 3 + 1] = e1 * inv;
        out[(size_t)(r0 + tid) * 3 + 2] = e2 * inv;
    }
}

// ---------------------------------------------------------------------------
extern "C" void kernel_launch(void* const* d_in, const int* in_sizes, int n_in,
                              void* d_out, int out_size, void* d_ws, size_t ws_size,
                              hipStream_t stream)
{
    const float* x    = (const float*)d_in[0];
    const float* wih1 = (const float*)d_in[1];
    const float* whh1 = (const float*)d_in[2];
    const float* bih1 = (const float*)d_in[3];
    const float* bhh1 = (const float*)d_in[4];
    const float* wih2 = (const float*)d_in[5];
    const float* whh2 = (const float*)d_in[6];
    const float* bih2 = (const float*)d_in[7];
    const float* bhh2 = (const float*)d_in[8];
    const float* wih3 = (const float*)d_in[9];
    const float* whh3 = (const float*)d_in[10];
    const float* bih3 = (const float*)d_in[11];
    const float* bhh3 = (const float*)d_in[12];
    const float* f1w  = (const float*)d_in[13];
    const float* f1b  = (const float*)d_in[14];
    const float* f2w  = (const float*)d_in[15];
    const float* f2b  = (const float*)d_in[16];
    const float* f3w  = (const float*)d_in[17];
    const float* f3b  = (const float*)d_in[18];
    float* outp = (float*)d_out;

    // workspace layout (fp32):
    //   xg : M * 512 floats (shared by xg1[256], xg2[512], xg3[256])  = 134.2 MB
    //   hb : M * 128 floats (shared by h1[64], h2[128], h3[64])       =  33.6 MB
    float* xg = (float*)d_ws;
    float* hb = xg + (size_t)M_SZ * 512;

    const int M = M_SZ, T = T_SZ;

    // Layer 1
    gemm_bias<<<dim3(256 / 64, M / 64), 256, 0, stream>>>(
        x, wih1, bih1, bhh1, xg, M, D_IN, 256);
    lstm_rec<64, 4><<<B_SZ / 4, 256, 0, stream>>>(xg, whh1, hb, T);

    // Layer 2
    gemm_bias<<<dim3(512 / 64, M / 64), 256, 0, stream>>>(
        hb, wih2, bih2, bhh2, xg, M, 64, 512);
    lstm_rec<128, 4><<<B_SZ / 4, 512, 0, stream>>>(xg, whh2, hb, T);

    // Layer 3
    gemm_bias<<<dim3(256 / 64, M / 64), 256, 0, stream>>>(
        hb, wih3, bih3, bhh3, xg, M, 128, 256);
    lstm_rec<64, 4><<<B_SZ / 4, 256, 0, stream>>>(xg, whh3, hb, T);

    // Head
    head_kernel<<<B_SZ / 16, 256, 0, stream>>>(
        hb, f1w, f1b, f2w, f2b, f3w, f3b, outp, T);
}

// Round 2
// 1491.359 us; speedup vs baseline: 1.2326x; 1.2326x over previous
//
#include <hip/hip_runtime.h>
#include <hip/hip_bf16.h>

#define B_SZ   1024
#define T_SZ   64
#define D_IN   1662
#define M_SZ   (B_SZ * T_SZ)   // 65536

typedef __attribute__((ext_vector_type(8))) short short8;
typedef __attribute__((ext_vector_type(4))) float f32x4;

// fp32 -> bf16 round-to-nearest-even (bit trick; inputs are finite)
__device__ __forceinline__ short f2bf(float f) {
    unsigned u = __builtin_bit_cast(unsigned, f);
    u += 0x7FFFu + ((u >> 16) & 1u);
    return (short)(u >> 16);
}

// ---------------------------------------------------------------------------
// MFMA GEMM: out[M,G] = A[M,K]fp32 @ W[G,K]fp32^T + (bi+bh), fp32 out.
// 128x128 tile, BK=32, 256 threads (4 waves, 2x2), 16x16x32 bf16 MFMA.
// A and W converted to bf16 during LDS staging (reg-staged, RNE).
// LDS rows padded to 40 shorts (80 B) -> max 2-way bank aliasing (free).
// Requires: M%128==0, G%128==0, K even.
// ---------------------------------------------------------------------------
__global__ __launch_bounds__(256) void gemm_mfma(
    const float* __restrict__ A, const float* __restrict__ W,
    const float* __restrict__ bi, const float* __restrict__ bh,
    float* __restrict__ out, int M, int K, int G)
{
    __shared__ __align__(16) short As[128][40];
    __shared__ __align__(16) short Ws[128][40];

    const int tid  = threadIdx.x;
    const int lane = tid & 63, wid = tid >> 6;
    const int wr = wid >> 1, wc = wid & 1;          // wave 2x2 over 128x128
    const int m0 = blockIdx.y * 128, g0 = blockIdx.x * 128;

    // staging assignment: thread -> (row, k-half)
    const int srow = tid >> 1;
    const int skg  = (tid & 1) * 16;
    const float* Arow = A + (size_t)(m0 + srow) * K;
    const float* Wrow = W + (size_t)(g0 + srow) * K;

    const int fr = lane & 15;            // fragment row/col within 16
    const int kq = (lane >> 4) * 8;      // k-offset of this lane's 8 elements

    f32x4 acc[4][4] = {};

    for (int k0 = 0; k0 < K; k0 += 32) {
        // ---- global loads (fp32, 8B-aligned float2, guarded) ----
        float av[16], wv[16];
        #pragma unroll
        for (int j = 0; j < 8; ++j) {
            const int kk = k0 + skg + 2 * j;
            if (kk < K) {
                float2 ta = *(const float2*)&Arow[kk];
                float2 tw = *(const float2*)&Wrow[kk];
                av[2 * j] = ta.x; av[2 * j + 1] = ta.y;
                wv[2 * j] = tw.x; wv[2 * j + 1] = tw.y;
            } else {
                av[2 * j] = 0.f; av[2 * j + 1] = 0.f;
                wv[2 * j] = 0.f; wv[2 * j + 1] = 0.f;
            }
        }

        __syncthreads();   // previous iteration's LDS reads complete

        // ---- convert + LDS write (2x 16B per tile) ----
        short8 pa0, pa1, pw0, pw1;
        #pragma unroll
        for (int j = 0; j < 8; ++j) {
            pa0[j] = f2bf(av[j]);     pa1[j] = f2bf(av[8 + j]);
            pw0[j] = f2bf(wv[j]);     pw1[j] = f2bf(wv[8 + j]);
        }
        *(short8*)&As[srow][skg]     = pa0;
        *(short8*)&As[srow][skg + 8] = pa1;
        *(short8*)&Ws[srow][skg]     = pw0;
        *(short8*)&Ws[srow][skg + 8] = pw1;

        __syncthreads();

        // ---- fragments + 16 MFMA ----
        short8 af[4], bf_[4];
        #pragma unroll
        for (int fm = 0; fm < 4; ++fm)
            af[fm] = *(const short8*)&As[wr * 64 + fm * 16 + fr][kq];
        #pragma unroll
        for (int fn = 0; fn < 4; ++fn)
            bf_[fn] = *(const short8*)&Ws[wc * 64 + fn * 16 + fr][kq];

        #pragma unroll
        for (int fm = 0; fm < 4; ++fm)
            #pragma unroll
            for (int fn = 0; fn < 4; ++fn)
                acc[fm][fn] = __builtin_amdgcn_mfma_f32_16x16x32_bf16(
                    af[fm], bf_[fn], acc[fm][fn], 0, 0, 0);
    }

    // ---- epilogue: C/D layout col=lane&15, row=(lane>>4)*4+j ----
    const int rbase = (lane >> 4) * 4;
    #pragma unroll
    for (int fn = 0; fn < 4; ++fn) {
        const int g = g0 + wc * 64 + fn * 16 + fr;
        const float bv = bi[g] + bh[g];
        #pragma unroll
        for (int fm = 0; fm < 4; ++fm) {
            const int mbase = m0 + wr * 64 + fm * 16 + rbase;
            #pragma unroll
            for (int j = 0; j < 4; ++j)
                out[(size_t)(mbase + j) * G + g] = acc[fm][fn][j] + bv;
        }
    }
}

// ---------------------------------------------------------------------------
// LSTM recurrence. One block handles RB batch rows for all T steps.
// 4H threads; thread j owns gate column j (w_hh row j in registers).
// Gate order (PyTorch): i, f, g, o.
// ---------------------------------------------------------------------------
__device__ __forceinline__ float sigmoid_f(float x) {
    return 1.0f / (1.0f + __expf(-x));
}
__device__ __forceinline__ float tanh_f(float x) {
    float a = fabsf(x);
    float e = __expf(2.0f * a);       // inf for large a -> r = 1
    float r = 1.0f - 2.0f / (e + 1.0f);
    return copysignf(r, x);
}

template<int H, int RB>
__global__ __launch_bounds__(4 * H) void lstm_rec(
    const float* __restrict__ xg,   // [B, T, 4H]  (input proj + both biases)
    const float* __restrict__ whh,  // [4H, H]
    float* __restrict__ hout,       // [B, T, H]
    int Tn)
{
    constexpr int G = 4 * H;
    const int tid = threadIdx.x;           // 0..G-1
    const int r0  = blockIdx.x * RB;

    __shared__ __align__(16) float h_lds[RB][H];
    __shared__ __align__(16) float g_lds[RB][G];

    // w_hh row for this thread's gate column (contiguous -> float4 loads)
    float wreg[H];
    {
        const float4* wp = (const float4*)(whh + (size_t)tid * H);
        #pragma unroll
        for (int q = 0; q < H / 4; ++q) {
            float4 v = wp[q];
            wreg[4 * q + 0] = v.x; wreg[4 * q + 1] = v.y;
            wreg[4 * q + 2] = v.z; wreg[4 * q + 3] = v.w;
        }
    }

    // cell-state ownership: RB*H == G, one item per thread
    const int cr = tid / H, cu = tid % H;
    float c = 0.f;
    h_lds[cr][cu] = 0.f;
    __syncthreads();

    for (int t = 0; t < Tn; ++t) {
        // Phase A: gates = xg[:,t,:] + h @ whh^T  (this thread: column tid)
        float acc[RB];
        #pragma unroll
        for (int r = 0; r < RB; ++r)
            acc[r] = xg[((size_t)(r0 + r) * Tn + t) * G + tid];
        #pragma unroll
        for (int r = 0; r < RB; ++r) {
            #pragma unroll
            for (int q = 0; q < H / 4; ++q) {
                float4 hv = *(const float4*)&h_lds[r][4 * q];
                acc[r] = fmaf(hv.x, wreg[4 * q + 0], acc[r]);
                acc[r] = fmaf(hv.y, wreg[4 * q + 1], acc[r]);
                acc[r] = fmaf(hv.z, wreg[4 * q + 2], acc[r]);
                acc[r] = fmaf(hv.w, wreg[4 * q + 3], acc[r]);
            }
        }
        #pragma unroll
        for (int r = 0; r < RB; ++r) g_lds[r][tid] = acc[r];
        __syncthreads();

        // Phase B: cell update for item (cr, cu)
        float gi = g_lds[cr][cu];
        float gf = g_lds[cr][H + cu];
        float gg = g_lds[cr][2 * H + cu];
        float go = g_lds[cr][3 * H + cu];
        float iv = sigmoid_f(gi);
        float fv = sigmoid_f(gf);
        float gv = tanh_f(gg);
        float ov = sigmoid_f(go);
        c = fmaf(fv, c, iv * gv);
        float h = ov * tanh_f(c);
        h_lds[cr][cu] = h;
        hout[((size_t)(r0 + cr) * Tn + t) * H + cu] = h;
        __syncthreads();
    }
}

// ---------------------------------------------------------------------------
// FC head: h3[:, T-1, :64] -> fc1(64) relu -> fc2(32) relu -> fc3(3) -> softmax
// 16 rows per block, 256 threads.
// ---------------------------------------------------------------------------
__global__ __launch_bounds__(256) void head_kernel(
    const float* __restrict__ h3,   // [B, T, 64]
    const float* __restrict__ w1, const float* __restrict__ b1,  // [64,64],[64]
    const float* __restrict__ w2, const float* __restrict__ b2,  // [32,64],[32]
    const float* __restrict__ w3, const float* __restrict__ b3,  // [3,32],[3]
    float* __restrict__ out, int Tn)
{
    __shared__ float W1[64][64];
    __shared__ float W2[32][64];
    __shared__ float W3[3][32];
    __shared__ float hin[16][64];
    __shared__ float a1[16][64];
    __shared__ float a2[16][32];
    __shared__ float lg[16][3];

    const int tid = threadIdx.x;
    const int r0 = blockIdx.x * 16;

    for (int i = tid; i < 64 * 64; i += 256) W1[i >> 6][i & 63] = w1[i];
    for (int i = tid; i < 32 * 64; i += 256) W2[i >> 6][i & 63] = w2[i];
    for (int i = tid; i < 3 * 32; i += 256) W3[i >> 5][i & 31] = w3[i];
    for (int i = tid; i < 16 * 64; i += 256) {
        int r = i >> 6, u = i & 63;
        hin[r][u] = h3[((size_t)(r0 + r) * Tn + (Tn - 1)) * 64 + u];
    }
    __syncthreads();

    for (int i = tid; i < 16 * 64; i += 256) {
        int r = i >> 6, j = i & 63;
        float s = b1[j];
        #pragma unroll
        for (int k = 0; k < 64; ++k) s = fmaf(hin[r][k], W1[j][k], s);
        a1[r][j] = fmaxf(s, 0.f);
    }
    __syncthreads();

    for (int i = tid; i < 16 * 32; i += 256) {
        int r = i >> 5, j = i & 31;
        float s = b2[j];
        #pragma unroll
        for (int k = 0; k < 64; ++k) s = fmaf(a1[r][k], W2[j][k], s);
        a2[r][j] = fmaxf(s, 0.f);
    }
    __syncthreads();

    for (int i = tid; i < 16 * 3; i += 256) {
        int r = i / 3, j = i % 3;
        float s = b3[j];
        #pragma unroll
        for (int k = 0; k < 32; ++k) s = fmaf(a2[r][k], W3[j][k], s);
        lg[r][j] = s;
    }
    __syncthreads();

    if (tid < 16) {
        float l0 = lg[tid][0], l1 = lg[tid][1], l2 = lg[tid][2];
        float m = fmaxf(l0, fmaxf(l1, l2));
        float e0 = __expf(l0 - m), e1 = __expf(l1 - m), e2 = __expf(l2 - m);
        float inv = 1.0f / (e0 + e1 + e2);
        out[(size_t)(r0 + tid) * 3 + 0] = e0 * inv;
        out[(size_t)(r0 + tid) * 3 + 1] = e1 * inv;
        out[(size_t)(r0 + tid) * 3 + 2] = e2 * inv;
    }
}

// ---------------------------------------------------------------------------
extern "C" void kernel_launch(void* const* d_in, const int* in_sizes, int n_in,
                              void* d_out, int out_size, void* d_ws, size_t ws_size,
                              hipStream_t stream)
{
    const float* x    = (const float*)d_in[0];
    const float* wih1 = (const float*)d_in[1];
    const float* whh1 = (const float*)d_in[2];
    const float* bih1 = (const float*)d_in[3];
    const float* bhh1 = (const float*)d_in[4];
    const float* wih2 = (const float*)d_in[5];
    const float* whh2 = (const float*)d_in[6];
    const float* bih2 = (const float*)d_in[7];
    const float* bhh2 = (const float*)d_in[8];
    const float* wih3 = (const float*)d_in[9];
    const float* whh3 = (const float*)d_in[10];
    const float* bih3 = (const float*)d_in[11];
    const float* bhh3 = (const float*)d_in[12];
    const float* f1w  = (const float*)d_in[13];
    const float* f1b  = (const float*)d_in[14];
    const float* f2w  = (const float*)d_in[15];
    const float* f2b  = (const float*)d_in[16];
    const float* f3w  = (const float*)d_in[17];
    const float* f3b  = (const float*)d_in[18];
    float* outp = (float*)d_out;

    // workspace layout (fp32):
    //   xg : M * 512 floats (shared by xg1[256], xg2[512], xg3[256])  = 134.2 MB
    //   hb : M * 128 floats (shared by h1[64], h2[128], h3[64])       =  33.6 MB
    float* xg = (float*)d_ws;
    float* hb = xg + (size_t)M_SZ * 512;

    const int M = M_SZ, T = T_SZ;

    // Layer 1
    gemm_mfma<<<dim3(256 / 128, M / 128), 256, 0, stream>>>(
        x, wih1, bih1, bhh1, xg, M, D_IN, 256);
    lstm_rec<64, 4><<<B_SZ / 4, 256, 0, stream>>>(xg, whh1, hb, T);

    // Layer 2
    gemm_mfma<<<dim3(512 / 128, M / 128), 256, 0, stream>>>(
        hb, wih2, bih2, bhh2, xg, M, 64, 512);
    lstm_rec<128, 4><<<B_SZ / 4, 512, 0, stream>>>(xg, whh2, hb, T);

    // Layer 3
    gemm_mfma<<<dim3(256 / 128, M / 128), 256, 0, stream>>>(
        hb, wih3, bih3, bhh3, xg, M, 128, 256);
    lstm_rec<64, 4><<<B_SZ / 4, 256, 0, stream>>>(xg, whh3, hb, T);

    // Head
    head_kernel<<<B_SZ / 16, 256, 0, stream>>>(
        hb, f1w, f1b, f2w, f2b, f3w, f3b, outp, T);
}

// Round 3
// 919.328 us; speedup vs baseline: 1.9996x; 1.6222x over previous
//
#include <hip/hip_runtime.h>
#include <hip/hip_bf16.h>

#define B_SZ   1024
#define T_SZ   64
#define D_IN   1662
#define D_INP  1664                 // padded to 32-multiple
#define M_SZ   (B_SZ * T_SZ)        // 65536

typedef __attribute__((ext_vector_type(8))) short short8;
typedef __attribute__((ext_vector_type(4))) float f32x4;
typedef unsigned short ushort_t;

// fp32 -> bf16 round-to-nearest-even (finite inputs)
__device__ __forceinline__ unsigned short f2bf(float f) {
    unsigned u = __builtin_bit_cast(unsigned, f);
    u += 0x7FFFu + ((u >> 16) & 1u);
    return (unsigned short)(u >> 16);
}

// async global->LDS, 16B per lane, dest = wave-uniform base + lane*16
#define GLD16(gp, lp) __builtin_amdgcn_global_load_lds(                        \
    (const __attribute__((address_space(1))) void*)(gp),                       \
    (__attribute__((address_space(3))) void*)(lp), 16, 0, 0)

// ---------------------------------------------------------------------------
// convert fp32 [R,K] -> bf16 [R,Kp], zero-padding columns K..Kp. Kp%8==0.
// One thread per 8 outputs; float2 loads (8B-aligned since K even).
// ---------------------------------------------------------------------------
__global__ __launch_bounds__(256) void convert_pad(
    const float* __restrict__ src, ushort_t* __restrict__ dst,
    int K, int Kp, long total_chunks)
{
    const int cpr = Kp >> 3;
    const long stride = (long)gridDim.x * blockDim.x;
    for (long idx = (long)blockIdx.x * blockDim.x + threadIdx.x;
         idx < total_chunks; idx += stride) {
        const int row  = (int)(idx / cpr);
        const int base = ((int)(idx % cpr)) << 3;
        const float* s = src + (size_t)row * K;
        short8 o;
        #pragma unroll
        for (int j = 0; j < 4; ++j) {
            const int k = base + 2 * j;
            float2 v = make_float2(0.f, 0.f);
            if (k < K) v = *(const float2*)(s + k);
            o[2 * j]     = (short)f2bf(v.x);
            o[2 * j + 1] = (short)f2bf(v.y);
        }
        *(short8*)(dst + (size_t)row * Kp + base) = o;
    }
}

// ---------------------------------------------------------------------------
// MFMA GEMM (m97 structure): out[M,G] = A[M,Kp]bf16 @ W[G,Kp]bf16^T + bias.
// 128x128 tile, BK=32, 256 threads (4 waves 2x2), global_load_lds staging,
// linear LDS [128][32], ds_read_b128 fragments, 16x16x32 bf16 MFMA.
// Requires M%128==0, G%128==0, Kp%32==0. fp32 out.
// ---------------------------------------------------------------------------
__global__ __launch_bounds__(256) void gemm_bf16(
    const ushort_t* __restrict__ A, const ushort_t* __restrict__ W,
    const float* __restrict__ bi, const float* __restrict__ bh,
    float* __restrict__ out, int Kp, int G)
{
    __shared__ __align__(16) ushort_t As[128 * 32];
    __shared__ __align__(16) ushort_t Ws[128 * 32];

    const int tid = threadIdx.x, lane = tid & 63, wid = tid >> 6;
    const int wr = wid >> 1, wc = wid & 1;
    const int m0 = blockIdx.y * 128, g0 = blockIdx.x * 128;

    // staging: wave w covers tile rows [w*32, w*32+32); 4 lanes per row (16B each)
    const int srow = wid * 32 + (lane >> 2);
    const int skel = (lane & 3) * 8;                 // ushort offset in row
    const ushort_t* Ag  = A + (size_t)(m0 + srow) * Kp + skel;
    const ushort_t* Ag2 = Ag + (size_t)16 * Kp;      // rows +16
    const ushort_t* Wg  = W + (size_t)(g0 + srow) * Kp + skel;
    const ushort_t* Wg2 = Wg + (size_t)16 * Kp;

    ushort_t* la0 = &As[wid * 1024];                 // wave chunk0 (1024B)
    ushort_t* la1 = la0 + 512;                       // wave chunk1
    ushort_t* lw0 = &Ws[wid * 1024];
    ushort_t* lw1 = lw0 + 512;

    const int fr = lane & 15;                        // fragment row/col
    const int kq = (lane >> 4) * 8;                  // k-offset (ushorts)

    f32x4 acc[4][4] = {};

    for (int k0 = 0; k0 < Kp; k0 += 32) {
        __syncthreads();                              // prev LDS reads done
        GLD16(Ag, la0);  GLD16(Ag2, la1);
        GLD16(Wg, lw0);  GLD16(Wg2, lw1);
        Ag += 32; Ag2 += 32; Wg += 32; Wg2 += 32;
        __syncthreads();                              // vmcnt(0) drained here

        short8 af[4], bfr[4];
        #pragma unroll
        for (int fm = 0; fm < 4; ++fm)
            af[fm] = *(const short8*)&As[(wr * 64 + fm * 16 + fr) * 32 + kq];
        #pragma unroll
        for (int fn = 0; fn < 4; ++fn)
            bfr[fn] = *(const short8*)&Ws[(wc * 64 + fn * 16 + fr) * 32 + kq];

        #pragma unroll
        for (int fm = 0; fm < 4; ++fm)
            #pragma unroll
            for (int fn = 0; fn < 4; ++fn)
                acc[fm][fn] = __builtin_amdgcn_mfma_f32_16x16x32_bf16(
                    af[fm], bfr[fn], acc[fm][fn], 0, 0, 0);
    }

    // epilogue: C/D layout col=lane&15, row=(lane>>4)*4+j (validated round 2)
    const int rbase = (lane >> 4) * 4;
    #pragma unroll
    for (int fn = 0; fn < 4; ++fn) {
        const int g = g0 + wc * 64 + fn * 16 + fr;
        const float bv = bi[g] + bh[g];
        #pragma unroll
        for (int fm = 0; fm < 4; ++fm) {
            const int mbase = m0 + wr * 64 + fm * 16 + rbase;
            #pragma unroll
            for (int j = 0; j < 4; ++j)
                out[(size_t)(mbase + j) * G + g] = acc[fm][fn][j] + bv;
        }
    }
}

// ---------------------------------------------------------------------------
// LSTM recurrence (unchanged math) + dual fp32/bf16 h output.
// ---------------------------------------------------------------------------
__device__ __forceinline__ float sigmoid_f(float x) {
    return 1.0f / (1.0f + __expf(-x));
}
__device__ __forceinline__ float tanh_f(float x) {
    float a = fabsf(x);
    float e = __expf(2.0f * a);
    float r = 1.0f - 2.0f / (e + 1.0f);
    return copysignf(r, x);
}

template<int H, int RB>
__global__ __launch_bounds__(4 * H) void lstm_rec(
    const float* __restrict__ xg,    // [B, T, 4H]
    const float* __restrict__ whh,   // [4H, H]
    float* __restrict__ hout,        // [B, T, H] fp32
    ushort_t* __restrict__ hout16,   // [B, T, H] bf16
    int Tn)
{
    constexpr int G = 4 * H;
    const int tid = threadIdx.x;
    const int r0  = blockIdx.x * RB;

    __shared__ __align__(16) float h_lds[RB][H];
    __shared__ __align__(16) float g_lds[RB][G];

    float wreg[H];
    {
        const float4* wp = (const float4*)(whh + (size_t)tid * H);
        #pragma unroll
        for (int q = 0; q < H / 4; ++q) {
            float4 v = wp[q];
            wreg[4 * q + 0] = v.x; wreg[4 * q + 1] = v.y;
            wreg[4 * q + 2] = v.z; wreg[4 * q + 3] = v.w;
        }
    }

    const int cr = tid / H, cu = tid % H;
    float c = 0.f;
    h_lds[cr][cu] = 0.f;
    __syncthreads();

    for (int t = 0; t < Tn; ++t) {
        float acc[RB];
        #pragma unroll
        for (int r = 0; r < RB; ++r)
            acc[r] = xg[((size_t)(r0 + r) * Tn + t) * G + tid];
        #pragma unroll
        for (int r = 0; r < RB; ++r) {
            #pragma unroll
            for (int q = 0; q < H / 4; ++q) {
                float4 hv = *(const float4*)&h_lds[r][4 * q];
                acc[r] = fmaf(hv.x, wreg[4 * q + 0], acc[r]);
                acc[r] = fmaf(hv.y, wreg[4 * q + 1], acc[r]);
                acc[r] = fmaf(hv.z, wreg[4 * q + 2], acc[r]);
                acc[r] = fmaf(hv.w, wreg[4 * q + 3], acc[r]);
            }
        }
        #pragma unroll
        for (int r = 0; r < RB; ++r) g_lds[r][tid] = acc[r];
        __syncthreads();

        float gi = g_lds[cr][cu];
        float gf = g_lds[cr][H + cu];
        float gg = g_lds[cr][2 * H + cu];
        float go = g_lds[cr][3 * H + cu];
        float iv = sigmoid_f(gi);
        float fv = sigmoid_f(gf);
        float gv = tanh_f(gg);
        float ov = sigmoid_f(go);
        c = fmaf(fv, c, iv * gv);
        float h = ov * tanh_f(c);
        h_lds[cr][cu] = h;
        const size_t oidx = ((size_t)(r0 + cr) * Tn + t) * H + cu;
        hout[oidx] = h;
        hout16[oidx] = f2bf(h);
        __syncthreads();
    }
}

// ---------------------------------------------------------------------------
// FC head (unchanged).
// ---------------------------------------------------------------------------
__global__ __launch_bounds__(256) void head_kernel(
    const float* __restrict__ h3,
    const float* __restrict__ w1, const float* __restrict__ b1,
    const float* __restrict__ w2, const float* __restrict__ b2,
    const float* __restrict__ w3, const float* __restrict__ b3,
    float* __restrict__ out, int Tn)
{
    __shared__ float W1[64][64];
    __shared__ float W2[32][64];
    __shared__ float W3[3][32];
    __shared__ float hin[16][64];
    __shared__ float a1[16][64];
    __shared__ float a2[16][32];
    __shared__ float lg[16][3];

    const int tid = threadIdx.x;
    const int r0 = blockIdx.x * 16;

    for (int i = tid; i < 64 * 64; i += 256) W1[i >> 6][i & 63] = w1[i];
    for (int i = tid; i < 32 * 64; i += 256) W2[i >> 6][i & 63] = w2[i];
    for (int i = tid; i < 3 * 32; i += 256) W3[i >> 5][i & 31] = w3[i];
    for (int i = tid; i < 16 * 64; i += 256) {
        int r = i >> 6, u = i & 63;
        hin[r][u] = h3[((size_t)(r0 + r) * Tn + (Tn - 1)) * 64 + u];
    }
    __syncthreads();

    for (int i = tid; i < 16 * 64; i += 256) {
        int r = i >> 6, j = i & 63;
        float s = b1[j];
        #pragma unroll
        for (int k = 0; k < 64; ++k) s = fmaf(hin[r][k], W1[j][k], s);
        a1[r][j] = fmaxf(s, 0.f);
    }
    __syncthreads();

    for (int i = tid; i < 16 * 32; i += 256) {
        int r = i >> 5, j = i & 31;
        float s = b2[j];
        #pragma unroll
        for (int k = 0; k < 64; ++k) s = fmaf(a1[r][k], W2[j][k], s);
        a2[r][j] = fmaxf(s, 0.f);
    }
    __syncthreads();

    for (int i = tid; i < 16 * 3; i += 256) {
        int r = i / 3, j = i % 3;
        float s = b3[j];
        #pragma unroll
        for (int k = 0; k < 32; ++k) s = fmaf(a2[r][k], W3[j][k], s);
        lg[r][j] = s;
    }
    __syncthreads();

    if (tid < 16) {
        float l0 = lg[tid][0], l1 = lg[tid][1], l2 = lg[tid][2];
        float m = fmaxf(l0, fmaxf(l1, l2));
        float e0 = __expf(l0 - m), e1 = __expf(l1 - m), e2 = __expf(l2 - m);
        float inv = 1.0f / (e0 + e1 + e2);
        out[(size_t)(r0 + tid) * 3 + 0] = e0 * inv;
        out[(size_t)(r0 + tid) * 3 + 1] = e1 * inv;
        out[(size_t)(r0 + tid) * 3 + 2] = e2 * inv;
    }
}

// ---------------------------------------------------------------------------
extern "C" void kernel_launch(void* const* d_in, const int* in_sizes, int n_in,
                              void* d_out, int out_size, void* d_ws, size_t ws_size,
                              hipStream_t stream)
{
    const float* x    = (const float*)d_in[0];
    const float* wih1 = (const float*)d_in[1];
    const float* whh1 = (const float*)d_in[2];
    const float* bih1 = (const float*)d_in[3];
    const float* bhh1 = (const float*)d_in[4];
    const float* wih2 = (const float*)d_in[5];
    const float* whh2 = (const float*)d_in[6];
    const float* bih2 = (const float*)d_in[7];
    const float* bhh2 = (const float*)d_in[8];
    const float* wih3 = (const float*)d_in[9];
    const float* whh3 = (const float*)d_in[10];
    const float* bih3 = (const float*)d_in[11];
    const float* bhh3 = (const float*)d_in[12];
    const float* f1w  = (const float*)d_in[13];
    const float* f1b  = (const float*)d_in[14];
    const float* f2w  = (const float*)d_in[15];
    const float* f2b  = (const float*)d_in[16];
    const float* f3w  = (const float*)d_in[17];
    const float* f3b  = (const float*)d_in[18];
    float* outp = (float*)d_out;

    // workspace layout (~336.5 MB):
    //   region A (218,103,808 B): xb16 [M,1664]bf16; after GEMM1 it is dead and
    //                             re-used as xg2/xg3 (fp32, <=134.2 MB)
    //   xg1  : 67,108,864 B   (fp32 [M,256])
    //   hb   : 33,554,432 B   (fp32 [M,128] max)
    //   hb16 : 16,777,216 B   (bf16 [M,128] max)
    //   w1b/w2b/w3b : bf16 weights (~1 MB)
    char* wsb = (char*)d_ws;
    ushort_t* xb16 = (ushort_t*)wsb;
    float*    xgA  = (float*)wsb;                       // alias (layers 2/3)
    size_t off = 218103808;
    float*    xg1  = (float*)(wsb + off);   off += 67108864;
    float*    hb   = (float*)(wsb + off);   off += 33554432;
    ushort_t* hb16 = (ushort_t*)(wsb + off); off += 16777216;
    ushort_t* w1b  = (ushort_t*)(wsb + off);
    ushort_t* w2b  = w1b + (size_t)256 * D_INP;
    ushort_t* w3b  = w2b + (size_t)512 * 64;

    const int T = T_SZ;

    // conversions
    convert_pad<<<2048, 256, 0, stream>>>(x, xb16, D_IN, D_INP,
                                          (long)M_SZ * (D_INP / 8));
    convert_pad<<<208, 256, 0, stream>>>(wih1, w1b, D_IN, D_INP,
                                         (long)256 * (D_INP / 8));
    convert_pad<<<16, 256, 0, stream>>>(wih2, w2b, 64, 64, (long)512 * 8);
    convert_pad<<<16, 256, 0, stream>>>(wih3, w3b, 128, 128, (long)256 * 16);

    // Layer 1
    gemm_bf16<<<dim3(2, M_SZ / 128), 256, 0, stream>>>(
        xb16, w1b, bih1, bhh1, xg1, D_INP, 256);
    lstm_rec<64, 4><<<B_SZ / 4, 256, 0, stream>>>(xg1, whh1, hb, hb16, T);

    // Layer 2
    gemm_bf16<<<dim3(4, M_SZ / 128), 256, 0, stream>>>(
        hb16, w2b, bih2, bhh2, xgA, 64, 512);
    lstm_rec<128, 4><<<B_SZ / 4, 512, 0, stream>>>(xgA, whh2, hb, hb16, T);

    // Layer 3
    gemm_bf16<<<dim3(2, M_SZ / 128), 256, 0, stream>>>(
        hb16, w3b, bih3, bhh3, xgA, 128, 256);
    lstm_rec<64, 4><<<B_SZ / 4, 256, 0, stream>>>(xgA, whh3, hb, hb16, T);

    // Head
    head_kernel<<<B_SZ / 16, 256, 0, stream>>>(
        hb, f1w, f1b, f2w, f2b, f3w, f3b, outp, T);
}

// Round 4
// 637.013 us; speedup vs baseline: 2.8857x; 1.4432x over previous
//
#include <hip/hip_runtime.h>
#include <hip/hip_bf16.h>

#define B_SZ   1024
#define T_SZ   64
#define D_IN   1662
#define D_INP  1664                 // padded to 32-multiple
#define M_SZ   (B_SZ * T_SZ)        // 65536

typedef __attribute__((ext_vector_type(8))) short short8;
typedef __attribute__((ext_vector_type(4))) float f32x4;
typedef unsigned short ushort_t;

// fp32 -> bf16 round-to-nearest-even (finite inputs)
__device__ __forceinline__ unsigned short f2bf(float f) {
    unsigned u = __builtin_bit_cast(unsigned, f);
    u += 0x7FFFu + ((u >> 16) & 1u);
    return (unsigned short)(u >> 16);
}

// async global->LDS, 16B per lane, dest = wave-uniform base + lane*16
#define GLD16(gp, lp) __builtin_amdgcn_global_load_lds(                        \
    (const __attribute__((address_space(1))) void*)(gp),                       \
    (__attribute__((address_space(3))) void*)(lp), 16, 0, 0)

__device__ __forceinline__ float sigmoid_f(float x) {
    return 1.0f / (1.0f + __expf(-x));
}
__device__ __forceinline__ float tanh_f(float x) {
    float a = fabsf(x);
    float e = __expf(2.0f * a);
    float r = 1.0f - 2.0f / (e + 1.0f);
    return copysignf(r, x);
}

// ---------------------------------------------------------------------------
// convert fp32 [R,K] -> bf16 [R,Kp], zero-padding columns K..Kp. Kp%8==0.
// ---------------------------------------------------------------------------
__global__ __launch_bounds__(256) void convert_pad(
    const float* __restrict__ src, ushort_t* __restrict__ dst,
    int K, int Kp, long total_chunks)
{
    const int cpr = Kp >> 3;
    const long stride = (long)gridDim.x * blockDim.x;
    for (long idx = (long)blockIdx.x * blockDim.x + threadIdx.x;
         idx < total_chunks; idx += stride) {
        const int row  = (int)(idx / cpr);
        const int base = ((int)(idx % cpr)) << 3;
        const float* s = src + (size_t)row * K;
        short8 o;
        #pragma unroll
        for (int j = 0; j < 4; ++j) {
            const int k = base + 2 * j;
            float2 v = make_float2(0.f, 0.f);
            if (k < K) v = *(const float2*)(s + k);
            o[2 * j]     = (short)f2bf(v.x);
            o[2 * j + 1] = (short)f2bf(v.y);
        }
        *(short8*)(dst + (size_t)row * Kp + base) = o;
    }
}

// ---------------------------------------------------------------------------
// MFMA GEMM (m97 structure): out[M,G] = A[M,Kp]bf16 @ W[G,Kp]bf16^T + bias.
// 128x128 tile, BK=32, 256 threads (4 waves 2x2), global_load_lds staging.
// ---------------------------------------------------------------------------
__global__ __launch_bounds__(256) void gemm_bf16(
    const ushort_t* __restrict__ A, const ushort_t* __restrict__ W,
    const float* __restrict__ bi, const float* __restrict__ bh,
    float* __restrict__ out, int Kp, int G)
{
    __shared__ __align__(16) ushort_t As[128 * 32];
    __shared__ __align__(16) ushort_t Ws[128 * 32];

    const int tid = threadIdx.x, lane = tid & 63, wid = tid >> 6;
    const int wr = wid >> 1, wc = wid & 1;
    const int m0 = blockIdx.y * 128, g0 = blockIdx.x * 128;

    const int srow = wid * 32 + (lane >> 2);
    const int skel = (lane & 3) * 8;
    const ushort_t* Ag  = A + (size_t)(m0 + srow) * Kp + skel;
    const ushort_t* Ag2 = Ag + (size_t)16 * Kp;
    const ushort_t* Wg  = W + (size_t)(g0 + srow) * Kp + skel;
    const ushort_t* Wg2 = Wg + (size_t)16 * Kp;

    ushort_t* la0 = &As[wid * 1024];
    ushort_t* la1 = la0 + 512;
    ushort_t* lw0 = &Ws[wid * 1024];
    ushort_t* lw1 = lw0 + 512;

    const int fr = lane & 15;
    const int kq = (lane >> 4) * 8;

    f32x4 acc[4][4] = {};

    for (int k0 = 0; k0 < Kp; k0 += 32) {
        __syncthreads();
        GLD16(Ag, la0);  GLD16(Ag2, la1);
        GLD16(Wg, lw0);  GLD16(Wg2, lw1);
        Ag += 32; Ag2 += 32; Wg += 32; Wg2 += 32;
        __syncthreads();

        short8 af[4], bfr[4];
        #pragma unroll
        for (int fm = 0; fm < 4; ++fm)
            af[fm] = *(const short8*)&As[(wr * 64 + fm * 16 + fr) * 32 + kq];
        #pragma unroll
        for (int fn = 0; fn < 4; ++fn)
            bfr[fn] = *(const short8*)&Ws[(wc * 64 + fn * 16 + fr) * 32 + kq];

        #pragma unroll
        for (int fm = 0; fm < 4; ++fm)
            #pragma unroll
            for (int fn = 0; fn < 4; ++fn)
                acc[fm][fn] = __builtin_amdgcn_mfma_f32_16x16x32_bf16(
                    af[fm], bfr[fn], acc[fm][fn], 0, 0, 0);
    }

    const int rbase = (lane >> 4) * 4;
    #pragma unroll
    for (int fn = 0; fn < 4; ++fn) {
        const int g = g0 + wc * 64 + fn * 16 + fr;
        const float bv = bi[g] + bh[g];
        #pragma unroll
        for (int fm = 0; fm < 4; ++fm) {
            const int mbase = m0 + wr * 64 + fm * 16 + rbase;
            #pragma unroll
            for (int j = 0; j < 4; ++j)
                out[(size_t)(mbase + j) * G + g] = acc[fm][fn][j] + bv;
        }
    }
}

// ---------------------------------------------------------------------------
// MFMA LSTM recurrence. 16 batch rows/block, 512 threads (8 waves).
// Per step: gates[16][4H] = h[16][H]bf16 @ whh[4H][H]bf16^T  (+ xg at gather).
// whh fragments live in registers (converted once). h in LDS, XOR-swizzled.
// ---------------------------------------------------------------------------
template<int H>
__global__ __launch_bounds__(512, 1) void lstm_rec_mfma(
    const float* __restrict__ xg,    // [B, T, 4H] (includes both biases)
    const float* __restrict__ whh,   // [4H, H] fp32
    ushort_t* __restrict__ hout16,   // [B, T, H] bf16 (nullable)
    float* __restrict__ hlast,       // [B, H] fp32 (nullable, t=T-1 only)
    int Tn)
{
    constexpr int G4  = 4 * H;
    constexpr int NTW = (G4 / 16) / 8;   // N-tiles per wave (H=128:4, H=64:2)
    constexpr int KS  = H / 32;          // K-steps (H=128:4, H=64:2)
    constexpr int CI  = H / 32;          // cell items per thread (16*H/512)
    constexpr int GS  = G4 + 4;          // gates LDS row stride (2-way max)
    constexpr int LOG = (H == 128) ? 7 : 6;

    __shared__ float    gates[16 * GS];
    __shared__ ushort_t hsh[16 * H];     // bf16 h, XOR-swizzled rows

    const int tid = threadIdx.x, lane = tid & 63, wid = tid >> 6;
    const int r0 = blockIdx.x * 16;
    const int fr = lane & 15, kq = (lane >> 4) * 8;
    const int colbase = wid * (NTW * 16);

    // --- B fragments from whh (fp32 -> bf16), once, into registers ---
    short8 breg[NTW][KS];
    #pragma unroll
    for (int nt = 0; nt < NTW; ++nt)
        #pragma unroll
        for (int ks = 0; ks < KS; ++ks) {
            const float* wp = whh + (size_t)(colbase + nt * 16 + fr) * H
                              + ks * 32 + kq;
            short8 b;
            #pragma unroll
            for (int j = 0; j < 8; ++j) b[j] = (short)f2bf(wp[j]);
            breg[nt][ks] = b;
        }

    // zero h
    for (int i = tid; i < 16 * H; i += 512) hsh[i] = 0;

    float c[CI];
    #pragma unroll
    for (int i = 0; i < CI; ++i) c[i] = 0.f;

    // xg prefetch (t=0)
    float xv[CI][4];
    #pragma unroll
    for (int i = 0; i < CI; ++i) {
        const int id = i * 512 + tid, row = id >> LOG, u = id & (H - 1);
        const float* p = xg + ((size_t)(r0 + row) * Tn + 0) * G4 + u;
        xv[i][0] = p[0]; xv[i][1] = p[H]; xv[i][2] = p[2 * H]; xv[i][3] = p[3 * H];
    }
    __syncthreads();

    for (int t = 0; t < Tn; ++t) {
        // A-fragments from swizzled h LDS
        short8 a[KS];
        #pragma unroll
        for (int ks = 0; ks < KS; ++ks) {
            const int k0 = ks * 32 + kq;
            a[ks] = *(const short8*)&hsh[fr * H + (k0 ^ ((fr & 7) << 3))];
        }

        f32x4 acc[NTW] = {};
        #pragma unroll
        for (int nt = 0; nt < NTW; ++nt)
            #pragma unroll
            for (int ks = 0; ks < KS; ++ks)
                acc[nt] = __builtin_amdgcn_mfma_f32_16x16x32_bf16(
                    a[ks], breg[nt][ks], acc[nt], 0, 0, 0);

        // scatter h@W^T to gates LDS (C layout: col=lane&15, row=(lane>>4)*4+j)
        const int rbase = (lane >> 4) * 4;
        #pragma unroll
        for (int nt = 0; nt < NTW; ++nt)
            #pragma unroll
            for (int j = 0; j < 4; ++j)
                gates[(rbase + j) * GS + colbase + nt * 16 + fr] = acc[nt][j];
        __syncthreads();

        // cell update (xv holds this step's xg)
        #pragma unroll
        for (int i = 0; i < CI; ++i) {
            const int id = i * 512 + tid, row = id >> LOG, u = id & (H - 1);
            const float gi = gates[row * GS + u]          + xv[i][0];
            const float gf = gates[row * GS + H + u]      + xv[i][1];
            const float gg = gates[row * GS + 2 * H + u]  + xv[i][2];
            const float go = gates[row * GS + 3 * H + u]  + xv[i][3];
            const float iv = sigmoid_f(gi);
            const float fv = sigmoid_f(gf);
            const float gv = tanh_f(gg);
            const float ov = sigmoid_f(go);
            c[i] = fmaf(fv, c[i], iv * gv);
            const float h = ov * tanh_f(c[i]);
            const ushort_t hb = f2bf(h);
            hsh[row * H + (u ^ ((row & 7) << 3))] = hb;
            if (hout16)
                hout16[((size_t)(r0 + row) * Tn + t) * H + u] = hb;
            if (hlast && t == Tn - 1)
                hlast[(size_t)(r0 + row) * H + u] = h;
        }

        // prefetch next step's xg
        if (t + 1 < Tn) {
            #pragma unroll
            for (int i = 0; i < CI; ++i) {
                const int id = i * 512 + tid, row = id >> LOG, u = id & (H - 1);
                const float* p = xg + ((size_t)(r0 + row) * Tn + (t + 1)) * G4 + u;
                xv[i][0] = p[0];     xv[i][1] = p[H];
                xv[i][2] = p[2 * H]; xv[i][3] = p[3 * H];
            }
        }
        __syncthreads();
    }
}

// ---------------------------------------------------------------------------
// FC head: hlast[B,64] -> fc1 relu -> fc2 relu -> fc3 -> softmax
// ---------------------------------------------------------------------------
__global__ __launch_bounds__(256) void head_kernel(
    const float* __restrict__ hlast,  // [B, 64]
    const float* __restrict__ w1, const float* __restrict__ b1,
    const float* __restrict__ w2, const float* __restrict__ b2,
    const float* __restrict__ w3, const float* __restrict__ b3,
    float* __restrict__ out)
{
    __shared__ float W1[64][64];
    __shared__ float W2[32][64];
    __shared__ float W3[3][32];
    __shared__ float hin[16][64];
    __shared__ float a1[16][64];
    __shared__ float a2[16][32];
    __shared__ float lg[16][3];

    const int tid = threadIdx.x;
    const int r0 = blockIdx.x * 16;

    for (int i = tid; i < 64 * 64; i += 256) W1[i >> 6][i & 63] = w1[i];
    for (int i = tid; i < 32 * 64; i += 256) W2[i >> 6][i & 63] = w2[i];
    for (int i = tid; i < 3 * 32; i += 256) W3[i >> 5][i & 31] = w3[i];
    for (int i = tid; i < 16 * 64; i += 256) {
        int r = i >> 6, u = i & 63;
        hin[r][u] = hlast[(size_t)(r0 + r) * 64 + u];
    }
    __syncthreads();

    for (int i = tid; i < 16 * 64; i += 256) {
        int r = i >> 6, j = i & 63;
        float s = b1[j];
        #pragma unroll
        for (int k = 0; k < 64; ++k) s = fmaf(hin[r][k], W1[j][k], s);
        a1[r][j] = fmaxf(s, 0.f);
    }
    __syncthreads();

    for (int i = tid; i < 16 * 32; i += 256) {
        int r = i >> 5, j = i & 31;
        float s = b2[j];
        #pragma unroll
        for (int k = 0; k < 64; ++k) s = fmaf(a1[r][k], W2[j][k], s);
        a2[r][j] = fmaxf(s, 0.f);
    }
    __syncthreads();

    for (int i = tid; i < 16 * 3; i += 256) {
        int r = i / 3, j = i % 3;
        float s = b3[j];
        #pragma unroll
        for (int k = 0; k < 32; ++k) s = fmaf(a2[r][k], W3[j][k], s);
        lg[r][j] = s;
    }
    __syncthreads();

    if (tid < 16) {
        float l0 = lg[tid][0], l1 = lg[tid][1], l2 = lg[tid][2];
        float m = fmaxf(l0, fmaxf(l1, l2));
        float e0 = __expf(l0 - m), e1 = __expf(l1 - m), e2 = __expf(l2 - m);
        float inv = 1.0f / (e0 + e1 + e2);
        out[(size_t)(r0 + tid) * 3 + 0] = e0 * inv;
        out[(size_t)(r0 + tid) * 3 + 1] = e1 * inv;
        out[(size_t)(r0 + tid) * 3 + 2] = e2 * inv;
    }
}

// ---------------------------------------------------------------------------
extern "C" void kernel_launch(void* const* d_in, const int* in_sizes, int n_in,
                              void* d_out, int out_size, void* d_ws, size_t ws_size,
                              hipStream_t stream)
{
    const float* x    = (const float*)d_in[0];
    const float* wih1 = (const float*)d_in[1];
    const float* whh1 = (const float*)d_in[2];
    const float* bih1 = (const float*)d_in[3];
    const float* bhh1 = (const float*)d_in[4];
    const float* wih2 = (const float*)d_in[5];
    const float* whh2 = (const float*)d_in[6];
    const float* bih2 = (const float*)d_in[7];
    const float* bhh2 = (const float*)d_in[8];
    const float* wih3 = (const float*)d_in[9];
    const float* whh3 = (const float*)d_in[10];
    const float* bih3 = (const float*)d_in[11];
    const float* bhh3 = (const float*)d_in[12];
    const float* f1w  = (const float*)d_in[13];
    const float* f1b  = (const float*)d_in[14];
    const float* f2w  = (const float*)d_in[15];
    const float* f2b  = (const float*)d_in[16];
    const float* f3w  = (const float*)d_in[17];
    const float* f3b  = (const float*)d_in[18];
    float* outp = (float*)d_out;

    // workspace layout (~302 MB):
    //   region A (218,103,808 B): xb16 [M,1664]bf16; dead after GEMM1 ->
    //                             re-used as xg2/xg3 (fp32, <=134.2 MB)
    //   xg1   : 67,108,864 B  (fp32 [M,256])
    //   hb16  : 16,777,216 B  (bf16 [M,128] max)
    //   hlast :    262,144 B  (fp32 [B,64])
    //   w1b/w2b/w3b : bf16 weights (~1 MB)
    char* wsb = (char*)d_ws;
    ushort_t* xb16 = (ushort_t*)wsb;
    float*    xgA  = (float*)wsb;                        // alias (layers 2/3)
    size_t off = 218103808;
    float*    xg1   = (float*)(wsb + off);    off += 67108864;
    ushort_t* hb16  = (ushort_t*)(wsb + off); off += 16777216;
    float*    hlast = (float*)(wsb + off);    off += 262144;
    ushort_t* w1b   = (ushort_t*)(wsb + off);
    ushort_t* w2b   = w1b + (size_t)256 * D_INP;
    ushort_t* w3b   = w2b + (size_t)512 * 64;

    const int T = T_SZ;

    // conversions
    convert_pad<<<2048, 256, 0, stream>>>(x, xb16, D_IN, D_INP,
                                          (long)M_SZ * (D_INP / 8));
    convert_pad<<<208, 256, 0, stream>>>(wih1, w1b, D_IN, D_INP,
                                         (long)256 * (D_INP / 8));
    convert_pad<<<16, 256, 0, stream>>>(wih2, w2b, 64, 64, (long)512 * 8);
    convert_pad<<<16, 256, 0, stream>>>(wih3, w3b, 128, 128, (long)256 * 16);

    // Layer 1
    gemm_bf16<<<dim3(2, M_SZ / 128), 256, 0, stream>>>(
        xb16, w1b, bih1, bhh1, xg1, D_INP, 256);
    lstm_rec_mfma<64><<<B_SZ / 16, 512, 0, stream>>>(
        xg1, whh1, hb16, nullptr, T);

    // Layer 2
    gemm_bf16<<<dim3(4, M_SZ / 128), 256, 0, stream>>>(
        hb16, w2b, bih2, bhh2, xgA, 64, 512);
    lstm_rec_mfma<128><<<B_SZ / 16, 512, 0, stream>>>(
        xgA, whh2, hb16, nullptr, T);

    // Layer 3
    gemm_bf16<<<dim3(2, M_SZ / 128), 256, 0, stream>>>(
        hb16, w3b, bih3, bhh3, xgA, 128, 256);
    lstm_rec_mfma<64><<<B_SZ / 16, 512, 0, stream>>>(
        xgA, whh3, nullptr, hlast, T);

    // Head
    head_kernel<<<B_SZ / 16, 256, 0, stream>>>(
        hlast, f1w, f1b, f2w, f2b, f3w, f3b, outp);
}

// Round 5
// 619.226 us; speedup vs baseline: 2.9686x; 1.0287x over previous
//
#include <hip/hip_runtime.h>
#include <hip/hip_bf16.h>

#define B_SZ   1024
#define T_SZ   64
#define D_IN   1662
#define D_INP  1664                 // padded to 32-multiple
#define M_SZ   (B_SZ * T_SZ)        // 65536

typedef __attribute__((ext_vector_type(8))) short short8;
typedef __attribute__((ext_vector_type(4))) float f32x4;
typedef unsigned short ushort_t;

// fp32 -> bf16 round-to-nearest-even (finite inputs)
__device__ __forceinline__ unsigned short f2bf(float f) {
    unsigned u = __builtin_bit_cast(unsigned, f);
    u += 0x7FFFu + ((u >> 16) & 1u);
    return (unsigned short)(u >> 16);
}
__device__ __forceinline__ float bf2f(ushort_t u) {
    return __builtin_bit_cast(float, (unsigned)u << 16);
}

// async global->LDS, 16B per lane, dest = wave-uniform base + lane*16
#define GLD16(gp, lp) __builtin_amdgcn_global_load_lds(                        \
    (const __attribute__((address_space(1))) void*)(gp),                       \
    (__attribute__((address_space(3))) void*)(lp), 16, 0, 0)

__device__ __forceinline__ float sigmoid_f(float x) {
    return 1.0f / (1.0f + __expf(-x));
}
__device__ __forceinline__ float tanh_f(float x) {
    float a = fabsf(x);
    float e = __expf(2.0f * a);
    float r = 1.0f - 2.0f / (e + 1.0f);
    return copysignf(r, x);
}

// ---------------------------------------------------------------------------
// convert fp32 [R,K] -> bf16 [R,Kp], zero-padding columns K..Kp. (weights only)
// ---------------------------------------------------------------------------
__global__ __launch_bounds__(256) void convert_pad(
    const float* __restrict__ src, ushort_t* __restrict__ dst,
    int K, int Kp, long total_chunks)
{
    const int cpr = Kp >> 3;
    const long stride = (long)gridDim.x * blockDim.x;
    for (long idx = (long)blockIdx.x * blockDim.x + threadIdx.x;
         idx < total_chunks; idx += stride) {
        const int row  = (int)(idx / cpr);
        const int base = ((int)(idx % cpr)) << 3;
        const float* s = src + (size_t)row * K;
        short8 o;
        #pragma unroll
        for (int j = 0; j < 4; ++j) {
            const int k = base + 2 * j;
            float2 v = make_float2(0.f, 0.f);
            if (k < K) v = *(const float2*)(s + k);
            o[2 * j]     = (short)f2bf(v.x);
            o[2 * j + 1] = (short)f2bf(v.y);
        }
        *(short8*)(dst + (size_t)row * Kp + base) = o;
    }
}

// ---------------------------------------------------------------------------
// Layer-1 GEMM with fused fp32->bf16 A-conversion:
// out[M,G]bf16 = A[M,K]fp32 @ W[G,Kp]bf16^T   (no bias).
// 128x128 tile, BK=32, 256 threads (4 waves 2x2).
// A staging: per wave-instr 16 lanes x float2 = one row's 128B BK slice,
// 4 rows contiguous per instr -> coalesced; convert+pack -> u32 ds_write.
// W staging: global_load_lds width 16.
// ---------------------------------------------------------------------------
__global__ __launch_bounds__(256) void gemm_a32(
    const float* __restrict__ A, const ushort_t* __restrict__ W,
    ushort_t* __restrict__ out, int K, int Kp, int G)
{
    __shared__ __align__(16) ushort_t As[128 * 32];
    __shared__ __align__(16) ushort_t Ws[128 * 32];

    const int tid = threadIdx.x, lane = tid & 63, wid = tid >> 6;
    const int wr = wid >> 1, wc = wid & 1;
    const int m0 = blockIdx.y * 128, g0 = blockIdx.x * 128;

    // A staging: thread -> base row wid*32 + (lane>>4) (+4j), col (lane&15)*2
    const int arow = wid * 32 + (lane >> 4);
    const int acol = (lane & 15) * 2;
    const float* Abase = A + (size_t)(m0 + arow) * K + acol;

    // W staging (GLD16): 4 lanes/row, rows wid*32+(lane>>2) and +16
    const int srow = wid * 32 + (lane >> 2);
    const int skel = (lane & 3) * 8;
    const ushort_t* Wg  = W + (size_t)(g0 + srow) * Kp + skel;
    const ushort_t* Wg2 = Wg + (size_t)16 * Kp;
    ushort_t* lw0 = &Ws[wid * 1024];
    ushort_t* lw1 = lw0 + 512;

    const int fr = lane & 15;
    const int kq = (lane >> 4) * 8;

    f32x4 acc[4][4] = {};

    const int nFull = K / 32;            // unguarded iterations

    for (int it = 0; it < nFull; ++it) {
        const int k0 = it * 32;
        float2 av[8];
        #pragma unroll
        for (int j = 0; j < 8; ++j)
            av[j] = *(const float2*)(Abase + (size_t)(4 * j) * K + k0);

        __syncthreads();                      // prev iter LDS reads done
        GLD16(Wg, lw0); GLD16(Wg2, lw1); Wg += 32; Wg2 += 32;
        #pragma unroll
        for (int j = 0; j < 8; ++j) {
            unsigned pk = (unsigned)f2bf(av[j].x) | ((unsigned)f2bf(av[j].y) << 16);
            *(unsigned*)&As[(arow + 4 * j) * 32 + acol] = pk;
        }
        __syncthreads();

        short8 af[4], bfr[4];
        #pragma unroll
        for (int fm = 0; fm < 4; ++fm)
            af[fm] = *(const short8*)&As[(wr * 64 + fm * 16 + fr) * 32 + kq];
        #pragma unroll
        for (int fn = 0; fn < 4; ++fn)
            bfr[fn] = *(const short8*)&Ws[(wc * 64 + fn * 16 + fr) * 32 + kq];
        #pragma unroll
        for (int fm = 0; fm < 4; ++fm)
            #pragma unroll
            for (int fn = 0; fn < 4; ++fn)
                acc[fm][fn] = __builtin_amdgcn_mfma_f32_16x16x32_bf16(
                    af[fm], bfr[fn], acc[fm][fn], 0, 0, 0);
    }

    if (nFull * 32 < Kp) {                    // guarded tail (k0 = nFull*32)
        const int k0 = nFull * 32;
        float2 av[8];
        const bool ok = (k0 + acol) < K;      // pair-valid (K even, acol even)
        #pragma unroll
        for (int j = 0; j < 8; ++j)
            av[j] = ok ? *(const float2*)(Abase + (size_t)(4 * j) * K + k0)
                       : make_float2(0.f, 0.f);

        __syncthreads();
        GLD16(Wg, lw0); GLD16(Wg2, lw1);
        #pragma unroll
        for (int j = 0; j < 8; ++j) {
            unsigned pk = (unsigned)f2bf(av[j].x) | ((unsigned)f2bf(av[j].y) << 16);
            *(unsigned*)&As[(arow + 4 * j) * 32 + acol] = pk;
        }
        __syncthreads();

        short8 af[4], bfr[4];
        #pragma unroll
        for (int fm = 0; fm < 4; ++fm)
            af[fm] = *(const short8*)&As[(wr * 64 + fm * 16 + fr) * 32 + kq];
        #pragma unroll
        for (int fn = 0; fn < 4; ++fn)
            bfr[fn] = *(const short8*)&Ws[(wc * 64 + fn * 16 + fr) * 32 + kq];
        #pragma unroll
        for (int fm = 0; fm < 4; ++fm)
            #pragma unroll
            for (int fn = 0; fn < 4; ++fn)
                acc[fm][fn] = __builtin_amdgcn_mfma_f32_16x16x32_bf16(
                    af[fm], bfr[fn], acc[fm][fn], 0, 0, 0);
    }

    // epilogue: bf16 out, no bias. C/D: col=lane&15, row=(lane>>4)*4+j
    const int rbase = (lane >> 4) * 4;
    #pragma unroll
    for (int fn = 0; fn < 4; ++fn) {
        const int g = g0 + wc * 64 + fn * 16 + fr;
        #pragma unroll
        for (int fm = 0; fm < 4; ++fm) {
            const int mbase = m0 + wr * 64 + fm * 16 + rbase;
            #pragma unroll
            for (int j = 0; j < 4; ++j)
                out[(size_t)(mbase + j) * G + g] = f2bf(acc[fm][fn][j]);
        }
    }
}

// ---------------------------------------------------------------------------
// Layers 2/3 GEMM: out[M,G]bf16 = A[M,Kp]bf16 @ W[G,Kp]bf16^T (no bias).
// m97 structure, 128x128 tile, BK=32, GLD16 staging both operands.
// ---------------------------------------------------------------------------
__global__ __launch_bounds__(256) void gemm_b16(
    const ushort_t* __restrict__ A, const ushort_t* __restrict__ W,
    ushort_t* __restrict__ out, int Kp, int G)
{
    __shared__ __align__(16) ushort_t As[128 * 32];
    __shared__ __align__(16) ushort_t Ws[128 * 32];

    const int tid = threadIdx.x, lane = tid & 63, wid = tid >> 6;
    const int wr = wid >> 1, wc = wid & 1;
    const int m0 = blockIdx.y * 128, g0 = blockIdx.x * 128;

    const int srow = wid * 32 + (lane >> 2);
    const int skel = (lane & 3) * 8;
    const ushort_t* Ag  = A + (size_t)(m0 + srow) * Kp + skel;
    const ushort_t* Ag2 = Ag + (size_t)16 * Kp;
    const ushort_t* Wg  = W + (size_t)(g0 + srow) * Kp + skel;
    const ushort_t* Wg2 = Wg + (size_t)16 * Kp;

    ushort_t* la0 = &As[wid * 1024];
    ushort_t* la1 = la0 + 512;
    ushort_t* lw0 = &Ws[wid * 1024];
    ushort_t* lw1 = lw0 + 512;

    const int fr = lane & 15;
    const int kq = (lane >> 4) * 8;

    f32x4 acc[4][4] = {};

    for (int k0 = 0; k0 < Kp; k0 += 32) {
        __syncthreads();
        GLD16(Ag, la0);  GLD16(Ag2, la1);
        GLD16(Wg, lw0);  GLD16(Wg2, lw1);
        Ag += 32; Ag2 += 32; Wg += 32; Wg2 += 32;
        __syncthreads();

        short8 af[4], bfr[4];
        #pragma unroll
        for (int fm = 0; fm < 4; ++fm)
            af[fm] = *(const short8*)&As[(wr * 64 + fm * 16 + fr) * 32 + kq];
        #pragma unroll
        for (int fn = 0; fn < 4; ++fn)
            bfr[fn] = *(const short8*)&Ws[(wc * 64 + fn * 16 + fr) * 32 + kq];

        #pragma unroll
        for (int fm = 0; fm < 4; ++fm)
            #pragma unroll
            for (int fn = 0; fn < 4; ++fn)
                acc[fm][fn] = __builtin_amdgcn_mfma_f32_16x16x32_bf16(
                    af[fm], bfr[fn], acc[fm][fn], 0, 0, 0);
    }

    const int rbase = (lane >> 4) * 4;
    #pragma unroll
    for (int fn = 0; fn < 4; ++fn) {
        const int g = g0 + wc * 64 + fn * 16 + fr;
        #pragma unroll
        for (int fm = 0; fm < 4; ++fm) {
            const int mbase = m0 + wr * 64 + fm * 16 + rbase;
            #pragma unroll
            for (int j = 0; j < 4; ++j)
                out[(size_t)(mbase + j) * G + g] = f2bf(acc[fm][fn][j]);
        }
    }
}

// ---------------------------------------------------------------------------
// MFMA LSTM recurrence. 16 batch rows/block, 512 threads (8 waves).
// xg is bf16 WITHOUT bias; biases added here in fp32 (preloaded registers).
// ---------------------------------------------------------------------------
template<int H>
__global__ __launch_bounds__(512, 1) void lstm_rec_mfma(
    const ushort_t* __restrict__ xg,  // [B, T, 4H] bf16, matmul only
    const float* __restrict__ whh,    // [4H, H] fp32
    const float* __restrict__ bih,    // [4H]
    const float* __restrict__ bhh,    // [4H]
    ushort_t* __restrict__ hout16,    // [B, T, H] bf16 (nullable)
    float* __restrict__ hlast,        // [B, H] fp32 (nullable, t=T-1 only)
    int Tn)
{
    constexpr int G4  = 4 * H;
    constexpr int NTW = (G4 / 16) / 8;   // N-tiles per wave
    constexpr int KS  = H / 32;          // K-steps
    constexpr int CI  = H / 32;          // cell items per thread
    constexpr int GS  = G4 + 4;          // gates LDS row stride
    constexpr int LOG = (H == 128) ? 7 : 6;

    __shared__ float    gates[16 * GS];
    __shared__ ushort_t hsh[16 * H];     // bf16 h, XOR-swizzled rows

    const int tid = threadIdx.x, lane = tid & 63, wid = tid >> 6;
    const int r0 = blockIdx.x * 16;
    const int fr = lane & 15, kq = (lane >> 4) * 8;
    const int colbase = wid * (NTW * 16);

    // B fragments from whh (fp32 -> bf16), once, into registers
    short8 breg[NTW][KS];
    #pragma unroll
    for (int nt = 0; nt < NTW; ++nt)
        #pragma unroll
        for (int ks = 0; ks < KS; ++ks) {
            const float* wp = whh + (size_t)(colbase + nt * 16 + fr) * H
                              + ks * 32 + kq;
            short8 b;
            #pragma unroll
            for (int j = 0; j < 8; ++j) b[j] = (short)f2bf(wp[j]);
            breg[nt][ks] = b;
        }

    // per-thread fp32 bias (gate columns fixed per thread)
    float b4[CI][4];
    #pragma unroll
    for (int i = 0; i < CI; ++i) {
        const int u = (i * 512 + tid) & (H - 1);
        b4[i][0] = bih[u]         + bhh[u];
        b4[i][1] = bih[H + u]     + bhh[H + u];
        b4[i][2] = bih[2 * H + u] + bhh[2 * H + u];
        b4[i][3] = bih[3 * H + u] + bhh[3 * H + u];
    }

    for (int i = tid; i < 16 * H; i += 512) hsh[i] = 0;

    float c[CI];
    #pragma unroll
    for (int i = 0; i < CI; ++i) c[i] = 0.f;

    // xg prefetch (t=0)
    ushort_t xv[CI][4];
    #pragma unroll
    for (int i = 0; i < CI; ++i) {
        const int id = i * 512 + tid, row = id >> LOG, u = id & (H - 1);
        const ushort_t* p = xg + ((size_t)(r0 + row) * Tn + 0) * G4 + u;
        xv[i][0] = p[0]; xv[i][1] = p[H]; xv[i][2] = p[2 * H]; xv[i][3] = p[3 * H];
    }
    __syncthreads();

    for (int t = 0; t < Tn; ++t) {
        // A-fragments from swizzled h LDS
        short8 a[KS];
        #pragma unroll
        for (int ks = 0; ks < KS; ++ks) {
            const int k0 = ks * 32 + kq;
            a[ks] = *(const short8*)&hsh[fr * H + (k0 ^ ((fr & 7) << 3))];
        }

        f32x4 acc[NTW] = {};
        #pragma unroll
        for (int nt = 0; nt < NTW; ++nt)
            #pragma unroll
            for (int ks = 0; ks < KS; ++ks)
                acc[nt] = __builtin_amdgcn_mfma_f32_16x16x32_bf16(
                    a[ks], breg[nt][ks], acc[nt], 0, 0, 0);

        // scatter h@W^T to gates LDS
        const int rbase = (lane >> 4) * 4;
        #pragma unroll
        for (int nt = 0; nt < NTW; ++nt)
            #pragma unroll
            for (int j = 0; j < 4; ++j)
                gates[(rbase + j) * GS + colbase + nt * 16 + fr] = acc[nt][j];
        __syncthreads();

        // cell update
        #pragma unroll
        for (int i = 0; i < CI; ++i) {
            const int id = i * 512 + tid, row = id >> LOG, u = id & (H - 1);
            const float gi = gates[row * GS + u]         + bf2f(xv[i][0]) + b4[i][0];
            const float gf = gates[row * GS + H + u]     + bf2f(xv[i][1]) + b4[i][1];
            const float gg = gates[row * GS + 2 * H + u] + bf2f(xv[i][2]) + b4[i][2];
            const float go = gates[row * GS + 3 * H + u] + bf2f(xv[i][3]) + b4[i][3];
            const float iv = sigmoid_f(gi);
            const float fv = sigmoid_f(gf);
            const float gv = tanh_f(gg);
            const float ov = sigmoid_f(go);
            c[i] = fmaf(fv, c[i], iv * gv);
            const float h = ov * tanh_f(c[i]);
            const ushort_t hb = f2bf(h);
            hsh[row * H + (u ^ ((row & 7) << 3))] = hb;
            if (hout16)
                hout16[((size_t)(r0 + row) * Tn + t) * H + u] = hb;
            if (hlast && t == Tn - 1)
                hlast[(size_t)(r0 + row) * H + u] = h;
        }

        // prefetch next step's xg
        if (t + 1 < Tn) {
            #pragma unroll
            for (int i = 0; i < CI; ++i) {
                const int id = i * 512 + tid, row = id >> LOG, u = id & (H - 1);
                const ushort_t* p = xg + ((size_t)(r0 + row) * Tn + (t + 1)) * G4 + u;
                xv[i][0] = p[0];     xv[i][1] = p[H];
                xv[i][2] = p[2 * H]; xv[i][3] = p[3 * H];
            }
        }
        __syncthreads();
    }
}

// ---------------------------------------------------------------------------
// FC head: hlast[B,64] -> fc1 relu -> fc2 relu -> fc3 -> softmax
// ---------------------------------------------------------------------------
__global__ __launch_bounds__(256) void head_kernel(
    const float* __restrict__ hlast,
    const float* __restrict__ w1, const float* __restrict__ b1,
    const float* __restrict__ w2, const float* __restrict__ b2,
    const float* __restrict__ w3, const float* __restrict__ b3,
    float* __restrict__ out)
{
    __shared__ float W1[64][64];
    __shared__ float W2[32][64];
    __shared__ float W3[3][32];
    __shared__ float hin[16][64];
    __shared__ float a1[16][64];
    __shared__ float a2[16][32];
    __shared__ float lg[16][3];

    const int tid = threadIdx.x;
    const int r0 = blockIdx.x * 16;

    for (int i = tid; i < 64 * 64; i += 256) W1[i >> 6][i & 63] = w1[i];
    for (int i = tid; i < 32 * 64; i += 256) W2[i >> 6][i & 63] = w2[i];
    for (int i = tid; i < 3 * 32; i += 256) W3[i >> 5][i & 31] = w3[i];
    for (int i = tid; i < 16 * 64; i += 256) {
        int r = i >> 6, u = i & 63;
        hin[r][u] = hlast[(size_t)(r0 + r) * 64 + u];
    }
    __syncthreads();

    for (int i = tid; i < 16 * 64; i += 256) {
        int r = i >> 6, j = i & 63;
        float s = b1[j];
        #pragma unroll
        for (int k = 0; k < 64; ++k) s = fmaf(hin[r][k], W1[j][k], s);
        a1[r][j] = fmaxf(s, 0.f);
    }
    __syncthreads();

    for (int i = tid; i < 16 * 32; i += 256) {
        int r = i >> 5, j = i & 31;
        float s = b2[j];
        #pragma unroll
        for (int k = 0; k < 64; ++k) s = fmaf(a1[r][k], W2[j][k], s);
        a2[r][j] = fmaxf(s, 0.f);
    }
    __syncthreads();

    for (int i = tid; i < 16 * 3; i += 256) {
        int r = i / 3, j = i % 3;
        float s = b3[j];
        #pragma unroll
        for (int k = 0; k < 32; ++k) s = fmaf(a2[r][k], W3[j][k], s);
        lg[r][j] = s;
    }
    __syncthreads();

    if (tid < 16) {
        float l0 = lg[tid][0], l1 = lg[tid][1], l2 = lg[tid][2];
        float m = fmaxf(l0, fmaxf(l1, l2));
        float e0 = __expf(l0 - m), e1 = __expf(l1 - m), e2 = __expf(l2 - m);
        float inv = 1.0f / (e0 + e1 + e2);
        out[(size_t)(r0 + tid) * 3 + 0] = e0 * inv;
        out[(size_t)(r0 + tid) * 3 + 1] = e1 * inv;
        out[(size_t)(r0 + tid) * 3 + 2] = e2 * inv;
    }
}

// ---------------------------------------------------------------------------
extern "C" void kernel_launch(void* const* d_in, const int* in_sizes, int n_in,
                              void* d_out, int out_size, void* d_ws, size_t ws_size,
                              hipStream_t stream)
{
    const float* x    = (const float*)d_in[0];
    const float* wih1 = (const float*)d_in[1];
    const float* whh1 = (const float*)d_in[2];
    const float* bih1 = (const float*)d_in[3];
    const float* bhh1 = (const float*)d_in[4];
    const float* wih2 = (const float*)d_in[5];
    const float* whh2 = (const float*)d_in[6];
    const float* bih2 = (const float*)d_in[7];
    const float* bhh2 = (const float*)d_in[8];
    const float* wih3 = (const float*)d_in[9];
    const float* whh3 = (const float*)d_in[10];
    const float* bih3 = (const float*)d_in[11];
    const float* bhh3 = (const float*)d_in[12];
    const float* f1w  = (const float*)d_in[13];
    const float* f1b  = (const float*)d_in[14];
    const float* f2w  = (const float*)d_in[15];
    const float* f2b  = (const float*)d_in[16];
    const float* f3w  = (const float*)d_in[17];
    const float* f3b  = (const float*)d_in[18];
    float* outp = (float*)d_out;

    // workspace layout (~85 MB):
    //   xgb   : 67,108,864 B  (bf16 [M,512] max; shared by layers 1/2/3)
    //   hb16  : 16,777,216 B  (bf16 [M,128] max)
    //   hlast :    262,144 B  (fp32 [B,64])
    //   w1b/w2b/w3b : bf16 weights (~1 MB)
    char* wsb = (char*)d_ws;
    size_t off = 0;
    ushort_t* xgb   = (ushort_t*)(wsb + off); off += 67108864;
    ushort_t* hb16  = (ushort_t*)(wsb + off); off += 16777216;
    float*    hlast = (float*)(wsb + off);    off += 262144;
    ushort_t* w1b   = (ushort_t*)(wsb + off);
    ushort_t* w2b   = w1b + (size_t)256 * D_INP;
    ushort_t* w3b   = w2b + (size_t)512 * 64;

    const int T = T_SZ;

    // weight conversions (tiny)
    convert_pad<<<208, 256, 0, stream>>>(wih1, w1b, D_IN, D_INP,
                                         (long)256 * (D_INP / 8));
    convert_pad<<<16, 256, 0, stream>>>(wih2, w2b, 64, 64, (long)512 * 8);
    convert_pad<<<16, 256, 0, stream>>>(wih3, w3b, 128, 128, (long)256 * 16);

    // Layer 1 (fused fp32->bf16 A staging)
    gemm_a32<<<dim3(2, M_SZ / 128), 256, 0, stream>>>(
        x, w1b, xgb, D_IN, D_INP, 256);
    lstm_rec_mfma<64><<<B_SZ / 16, 512, 0, stream>>>(
        xgb, whh1, bih1, bhh1, hb16, nullptr, T);

    // Layer 2
    gemm_b16<<<dim3(4, M_SZ / 128), 256, 0, stream>>>(
        hb16, w2b, xgb, 64, 512);
    lstm_rec_mfma<128><<<B_SZ / 16, 512, 0, stream>>>(
        xgb, whh2, bih2, bhh2, hb16, nullptr, T);

    // Layer 3
    gemm_b16<<<dim3(2, M_SZ / 128), 256, 0, stream>>>(
        hb16, w3b, xgb, 128, 256);
    lstm_rec_mfma<64><<<B_SZ / 16, 512, 0, stream>>>(
        xgb, whh3, bih3, bhh3, nullptr, hlast, T);

    // Head
    head_kernel<<<B_SZ / 16, 256, 0, stream>>>(
        hlast, f1w, f1b, f2w, f2b, f3w, f3b, outp);
}

// Round 6
// 516.511 us; speedup vs baseline: 3.5590x; 1.1989x over previous
//
#include <hip/hip_runtime.h>
#include <hip/hip_bf16.h>

#define B_SZ   1024
#define T_SZ   64
#define D_IN   1662
#define D_INP  1664                 // padded to 32-multiple
#define M_SZ   (B_SZ * T_SZ)        // 65536

typedef __attribute__((ext_vector_type(8))) short short8;
typedef __attribute__((ext_vector_type(4))) float f32x4;
typedef unsigned short ushort_t;

// fp32 -> bf16 round-to-nearest-even (finite inputs)
__device__ __forceinline__ unsigned short f2bf(float f) {
    unsigned u = __builtin_bit_cast(unsigned, f);
    u += 0x7FFFu + ((u >> 16) & 1u);
    return (unsigned short)(u >> 16);
}
__device__ __forceinline__ float bf2f(ushort_t u) {
    return __builtin_bit_cast(float, (unsigned)u << 16);
}

// async global->LDS, 16B per lane, dest = wave-uniform base + lane*16
#define GLD16(gp, lp) __builtin_amdgcn_global_load_lds(                        \
    (const __attribute__((address_space(1))) void*)(gp),                       \
    (__attribute__((address_space(3))) void*)(lp), 16, 0, 0)

__device__ __forceinline__ float sigmoid_f(float x) {
    return 1.0f / (1.0f + __expf(-x));
}
__device__ __forceinline__ float tanh_f(float x) {
    float a = fabsf(x);
    float e = __expf(2.0f * a);
    float r = 1.0f - 2.0f / (e + 1.0f);
    return copysignf(r, x);
}

// ---------------------------------------------------------------------------
// convert fp32 [R,K] -> bf16 [R,Kp], zero-padding columns K..Kp. (weights only)
// ---------------------------------------------------------------------------
__global__ __launch_bounds__(256) void convert_pad(
    const float* __restrict__ src, ushort_t* __restrict__ dst,
    int K, int Kp, long total_chunks)
{
    const int cpr = Kp >> 3;
    const long stride = (long)gridDim.x * blockDim.x;
    for (long idx = (long)blockIdx.x * blockDim.x + threadIdx.x;
         idx < total_chunks; idx += stride) {
        const int row  = (int)(idx / cpr);
        const int base = ((int)(idx % cpr)) << 3;
        const float* s = src + (size_t)row * K;
        short8 o;
        #pragma unroll
        for (int j = 0; j < 4; ++j) {
            const int k = base + 2 * j;
            float2 v = make_float2(0.f, 0.f);
            if (k < K) v = *(const float2*)(s + k);
            o[2 * j]     = (short)f2bf(v.x);
            o[2 * j + 1] = (short)f2bf(v.y);
        }
        *(short8*)(dst + (size_t)row * Kp + base) = o;
    }
}

// ---------------------------------------------------------------------------
// Layer-1 GEMM: out[M,256]bf16 = A[M,K]fp32 @ W[256,Kp]bf16^T.
// 128x256 tile (full G per block -> A read ONCE), BK=32, 512 threads
// (8 waves, 2x4). A: reg-staged fp32->bf16, one 16B ds_write/thread/iter.
// W: 2x global_load_lds width-16.
// ---------------------------------------------------------------------------
__global__ __launch_bounds__(512) void gemm_l1(
    const float* __restrict__ A, const ushort_t* __restrict__ W,
    ushort_t* __restrict__ out)
{
    constexpr int K = D_IN, Kp = D_INP, G = 256;
    __shared__ __align__(16) ushort_t As[128 * 32];
    __shared__ __align__(16) ushort_t Ws[256 * 32];

    const int tid = threadIdx.x, lane = tid & 63, wid = tid >> 6;
    const int wr = wid >> 2, wc = wid & 3;       // 2x4 wave grid
    const int m0 = blockIdx.x * 128;

    // A staging: thread -> row tid>>2 (0..127), 8 floats at col (tid&3)*8
    const int arow  = tid >> 2;
    const int acolb = (tid & 3) * 8;
    const float* Abase = A + (size_t)(m0 + arow) * K + acolb;

    // W staging: row wid*16+(lane>>2) (+128), 16B at col (lane&3)*8
    const int wrow = wid * 16 + (lane >> 2);
    const ushort_t* Wg0 = W + (size_t)wrow * Kp + (lane & 3) * 8;
    const ushort_t* Wg1 = Wg0 + (size_t)128 * Kp;
    ushort_t* lw0 = &Ws[wid * 512];
    ushort_t* lw1 = lw0 + 4096;

    const int fr = lane & 15, kq = (lane >> 4) * 8;

    f32x4 acc[4][4] = {};
    const int nFull = K / 32;                    // 51 full iters + 1 tail

    for (int it = 0; it <= nFull; ++it) {
        const int k0 = it * 32;
        float2 av[4];
        if (it < nFull) {
            #pragma unroll
            for (int j = 0; j < 4; ++j)
                av[j] = *(const float2*)(Abase + k0 + 2 * j);
        } else {
            #pragma unroll
            for (int j = 0; j < 4; ++j) {
                const int kk = k0 + acolb + 2 * j;
                av[j] = (kk < K) ? *(const float2*)(Abase + k0 + 2 * j)
                                 : make_float2(0.f, 0.f);
            }
        }

        __syncthreads();                          // prev iter LDS reads done
        GLD16(Wg0, lw0); GLD16(Wg1, lw1);
        Wg0 += 32; Wg1 += 32;
        short8 pk;
        #pragma unroll
        for (int j = 0; j < 4; ++j) {
            pk[2 * j]     = (short)f2bf(av[j].x);
            pk[2 * j + 1] = (short)f2bf(av[j].y);
        }
        *(short8*)&As[arow * 32 + acolb] = pk;
        __syncthreads();                          // staging (incl. vmcnt) done

        short8 af[4], bfr[4];
        #pragma unroll
        for (int fm = 0; fm < 4; ++fm)
            af[fm] = *(const short8*)&As[(wr * 64 + fm * 16 + fr) * 32 + kq];
        #pragma unroll
        for (int fn = 0; fn < 4; ++fn)
            bfr[fn] = *(const short8*)&Ws[(wc * 64 + fn * 16 + fr) * 32 + kq];
        #pragma unroll
        for (int fm = 0; fm < 4; ++fm)
            #pragma unroll
            for (int fn = 0; fn < 4; ++fn)
                acc[fm][fn] = __builtin_amdgcn_mfma_f32_16x16x32_bf16(
                    af[fm], bfr[fn], acc[fm][fn], 0, 0, 0);
    }

    // epilogue: bf16, no bias. C/D: col=lane&15, row=(lane>>4)*4+j
    const int rbase = (lane >> 4) * 4;
    #pragma unroll
    for (int fn = 0; fn < 4; ++fn) {
        const int g = wc * 64 + fn * 16 + fr;
        #pragma unroll
        for (int fm = 0; fm < 4; ++fm) {
            const int mbase = m0 + wr * 64 + fm * 16 + rbase;
            #pragma unroll
            for (int j = 0; j < 4; ++j)
                out[(size_t)(mbase + j) * G + g] = f2bf(acc[fm][fn][j]);
        }
    }
}

// ---------------------------------------------------------------------------
// Layers 2/3 GEMM: out[M,G]bf16 = A[M,Kp]bf16 @ W[G,Kp]bf16^T (no bias).
// m97 structure, 128x128 tile, BK=32, GLD16 staging both operands.
// ---------------------------------------------------------------------------
__global__ __launch_bounds__(256) void gemm_b16(
    const ushort_t* __restrict__ A, const ushort_t* __restrict__ W,
    ushort_t* __restrict__ out, int Kp, int G)
{
    __shared__ __align__(16) ushort_t As[128 * 32];
    __shared__ __align__(16) ushort_t Ws[128 * 32];

    const int tid = threadIdx.x, lane = tid & 63, wid = tid >> 6;
    const int wr = wid >> 1, wc = wid & 1;
    const int m0 = blockIdx.y * 128, g0 = blockIdx.x * 128;

    const int srow = wid * 32 + (lane >> 2);
    const int skel = (lane & 3) * 8;
    const ushort_t* Ag  = A + (size_t)(m0 + srow) * Kp + skel;
    const ushort_t* Ag2 = Ag + (size_t)16 * Kp;
    const ushort_t* Wg  = W + (size_t)(g0 + srow) * Kp + skel;
    const ushort_t* Wg2 = Wg + (size_t)16 * Kp;

    ushort_t* la0 = &As[wid * 1024];
    ushort_t* la1 = la0 + 512;
    ushort_t* lw0 = &Ws[wid * 1024];
    ushort_t* lw1 = lw0 + 512;

    const int fr = lane & 15;
    const int kq = (lane >> 4) * 8;

    f32x4 acc[4][4] = {};

    for (int k0 = 0; k0 < Kp; k0 += 32) {
        __syncthreads();
        GLD16(Ag, la0);  GLD16(Ag2, la1);
        GLD16(Wg, lw0);  GLD16(Wg2, lw1);
        Ag += 32; Ag2 += 32; Wg += 32; Wg2 += 32;
        __syncthreads();

        short8 af[4], bfr[4];
        #pragma unroll
        for (int fm = 0; fm < 4; ++fm)
            af[fm] = *(const short8*)&As[(wr * 64 + fm * 16 + fr) * 32 + kq];
        #pragma unroll
        for (int fn = 0; fn < 4; ++fn)
            bfr[fn] = *(const short8*)&Ws[(wc * 64 + fn * 16 + fr) * 32 + kq];

        #pragma unroll
        for (int fm = 0; fm < 4; ++fm)
            #pragma unroll
            for (int fn = 0; fn < 4; ++fn)
                acc[fm][fn] = __builtin_amdgcn_mfma_f32_16x16x32_bf16(
                    af[fm], bfr[fn], acc[fm][fn], 0, 0, 0);
    }

    const int rbase = (lane >> 4) * 4;
    #pragma unroll
    for (int fn = 0; fn < 4; ++fn) {
        const int g = g0 + wc * 64 + fn * 16 + fr;
        #pragma unroll
        for (int fm = 0; fm < 4; ++fm) {
            const int mbase = m0 + wr * 64 + fm * 16 + rbase;
            #pragma unroll
            for (int j = 0; j < 4; ++j)
                out[(size_t)(mbase + j) * G + g] = f2bf(acc[fm][fn][j]);
        }
    }
}

// ---------------------------------------------------------------------------
// Gate-grouped MFMA LSTM. 16 batch rows/block, 4H threads (H/16 waves).
// Wave wid computes ALL FOUR gates of units wid*16..wid*16+15 (breg[4][KS]),
// so each lane holds {i,f,g,o} of one unit for its 4 rows in-register:
// no gates-LDS round trip. h kept bf16 in LDS (XOR-swizzled rows).
// ---------------------------------------------------------------------------
template<int H>
__global__ __launch_bounds__(4 * H, 1) void lstm_fused(
    const ushort_t* __restrict__ xg,  // [B,T,4H] bf16, matmul only (no bias)
    const float* __restrict__ whh,    // [4H,H] fp32
    const float* __restrict__ bih, const float* __restrict__ bhh,
    ushort_t* __restrict__ hout16,    // [B,T,H] bf16 (nullable)
    float* __restrict__ hlast,        // [B,H] fp32 (nullable)
    int Tn)
{
    constexpr int G4 = 4 * H;
    constexpr int KS = H / 32;
    constexpr int NT = 4 * H;

    __shared__ ushort_t hsh[16 * H];

    const int tid = threadIdx.x, lane = tid & 63, wid = tid >> 6;
    const int r0 = blockIdx.x * 16;
    const int fr = lane & 15, kq = (lane >> 4) * 8;
    const int u = wid * 16 + fr;              // this lane's unit
    const int rbase = (lane >> 4) * 4;        // this lane's row base

    // B fragments: column (g*H + u) of whh^T, K-slice ks*32+kq
    short8 breg[4][KS];
    #pragma unroll
    for (int g = 0; g < 4; ++g)
        #pragma unroll
        for (int ks = 0; ks < KS; ++ks) {
            const float* wp = whh + (size_t)(g * H + u) * H + ks * 32 + kq;
            short8 b;
            #pragma unroll
            for (int j = 0; j < 8; ++j) b[j] = (short)f2bf(wp[j]);
            breg[g][ks] = b;
        }

    float bias[4];
    #pragma unroll
    for (int g = 0; g < 4; ++g) bias[g] = bih[g * H + u] + bhh[g * H + u];

    for (int i = tid; i < 16 * H; i += NT) hsh[i] = 0;

    float c[4] = {0.f, 0.f, 0.f, 0.f};

    // xg prefetch (t=0): xv[j][g] for row rbase+j, gate g, unit u
    ushort_t xv[4][4];
    #pragma unroll
    for (int j = 0; j < 4; ++j) {
        const ushort_t* p = xg + ((size_t)(r0 + rbase + j) * Tn) * G4 + u;
        #pragma unroll
        for (int g = 0; g < 4; ++g) xv[j][g] = p[g * H];
    }
    __syncthreads();

    for (int t = 0; t < Tn; ++t) {
        // A-fragments (h) from swizzled LDS
        short8 a[KS];
        #pragma unroll
        for (int ks = 0; ks < KS; ++ks) {
            const int k0 = ks * 32 + kq;
            a[ks] = *(const short8*)&hsh[fr * H + (k0 ^ ((fr & 7) << 3))];
        }
        __syncthreads();                      // all reads done before writes

        f32x4 acc[4] = {};
        #pragma unroll
        for (int g = 0; g < 4; ++g)
            #pragma unroll
            for (int ks = 0; ks < KS; ++ks)
                acc[g] = __builtin_amdgcn_mfma_f32_16x16x32_bf16(
                    a[ks], breg[g][ks], acc[g], 0, 0, 0);

        // cell update fully in-register (C/D: col=lane&15=unit, row=rbase+j)
        #pragma unroll
        for (int j = 0; j < 4; ++j) {
            const int row = rbase + j;
            const float gi = acc[0][j] + bf2f(xv[j][0]) + bias[0];
            const float gf = acc[1][j] + bf2f(xv[j][1]) + bias[1];
            const float gg = acc[2][j] + bf2f(xv[j][2]) + bias[2];
            const float go = acc[3][j] + bf2f(xv[j][3]) + bias[3];
            const float iv = sigmoid_f(gi);
            const float fv = sigmoid_f(gf);
            const float gv = tanh_f(gg);
            const float ov = sigmoid_f(go);
            c[j] = fmaf(fv, c[j], iv * gv);
            const float h = ov * tanh_f(c[j]);
            const ushort_t hb = f2bf(h);
            hsh[row * H + (u ^ ((row & 7) << 3))] = hb;
            if (hout16)
                hout16[((size_t)(r0 + row) * Tn + t) * H + u] = hb;
            if (hlast && t == Tn - 1)
                hlast[(size_t)(r0 + row) * H + u] = h;
        }

        // prefetch next step's xg
        if (t + 1 < Tn) {
            #pragma unroll
            for (int j = 0; j < 4; ++j) {
                const ushort_t* p =
                    xg + ((size_t)(r0 + rbase + j) * Tn + (t + 1)) * G4 + u;
                #pragma unroll
                for (int g = 0; g < 4; ++g) xv[j][g] = p[g * H];
            }
        }
        __syncthreads();                      // h visible for next step
    }
}

// ---------------------------------------------------------------------------
// FC head: hlast[B,64] -> fc1 relu -> fc2 relu -> fc3 -> softmax
// ---------------------------------------------------------------------------
__global__ __launch_bounds__(256) void head_kernel(
    const float* __restrict__ hlast,
    const float* __restrict__ w1, const float* __restrict__ b1,
    const float* __restrict__ w2, const float* __restrict__ b2,
    const float* __restrict__ w3, const float* __restrict__ b3,
    float* __restrict__ out)
{
    __shared__ float W1[64][64];
    __shared__ float W2[32][64];
    __shared__ float W3[3][32];
    __shared__ float hin[16][64];
    __shared__ float a1[16][64];
    __shared__ float a2[16][32];
    __shared__ float lg[16][3];

    const int tid = threadIdx.x;
    const int r0 = blockIdx.x * 16;

    for (int i = tid; i < 64 * 64; i += 256) W1[i >> 6][i & 63] = w1[i];
    for (int i = tid; i < 32 * 64; i += 256) W2[i >> 6][i & 63] = w2[i];
    for (int i = tid; i < 3 * 32; i += 256) W3[i >> 5][i & 31] = w3[i];
    for (int i = tid; i < 16 * 64; i += 256) {
        int r = i >> 6, u = i & 63;
        hin[r][u] = hlast[(size_t)(r0 + r) * 64 + u];
    }
    __syncthreads();

    for (int i = tid; i < 16 * 64; i += 256) {
        int r = i >> 6, j = i & 63;
        float s = b1[j];
        #pragma unroll
        for (int k = 0; k < 64; ++k) s = fmaf(hin[r][k], W1[j][k], s);
        a1[r][j] = fmaxf(s, 0.f);
    }
    __syncthreads();

    for (int i = tid; i < 16 * 32; i += 256) {
        int r = i >> 5, j = i & 31;
        float s = b2[j];
        #pragma unroll
        for (int k = 0; k < 64; ++k) s = fmaf(a1[r][k], W2[j][k], s);
        a2[r][j] = fmaxf(s, 0.f);
    }
    __syncthreads();

    for (int i = tid; i < 16 * 3; i += 256) {
        int r = i / 3, j = i % 3;
        float s = b3[j];
        #pragma unroll
        for (int k = 0; k < 32; ++k) s = fmaf(a2[r][k], W3[j][k], s);
        lg[r][j] = s;
    }
    __syncthreads();

    if (tid < 16) {
        float l0 = lg[tid][0], l1 = lg[tid][1], l2 = lg[tid][2];
        float m = fmaxf(l0, fmaxf(l1, l2));
        float e0 = __expf(l0 - m), e1 = __expf(l1 - m), e2 = __expf(l2 - m);
        float inv = 1.0f / (e0 + e1 + e2);
        out[(size_t)(r0 + tid) * 3 + 0] = e0 * inv;
        out[(size_t)(r0 + tid) * 3 + 1] = e1 * inv;
        out[(size_t)(r0 + tid) * 3 + 2] = e2 * inv;
    }
}

// ---------------------------------------------------------------------------
extern "C" void kernel_launch(void* const* d_in, const int* in_sizes, int n_in,
                              void* d_out, int out_size, void* d_ws, size_t ws_size,
                              hipStream_t stream)
{
    const float* x    = (const float*)d_in[0];
    const float* wih1 = (const float*)d_in[1];
    const float* whh1 = (const float*)d_in[2];
    const float* bih1 = (const float*)d_in[3];
    const float* bhh1 = (const float*)d_in[4];
    const float* wih2 = (const float*)d_in[5];
    const float* whh2 = (const float*)d_in[6];
    const float* bih2 = (const float*)d_in[7];
    const float* bhh2 = (const float*)d_in[8];
    const float* wih3 = (const float*)d_in[9];
    const float* whh3 = (const float*)d_in[10];
    const float* bih3 = (const float*)d_in[11];
    const float* bhh3 = (const float*)d_in[12];
    const float* f1w  = (const float*)d_in[13];
    const float* f1b  = (const float*)d_in[14];
    const float* f2w  = (const float*)d_in[15];
    const float* f2b  = (const float*)d_in[16];
    const float* f3w  = (const float*)d_in[17];
    const float* f3b  = (const float*)d_in[18];
    float* outp = (float*)d_out;

    // workspace layout (~85 MB):
    //   xgb   : 67,108,864 B  (bf16 [M,512] max; shared by layers 1/2/3)
    //   hb16  : 16,777,216 B  (bf16 [M,128] max)
    //   hlast :    262,144 B  (fp32 [B,64])
    //   w1b/w2b/w3b : bf16 weights (~1 MB)
    char* wsb = (char*)d_ws;
    size_t off = 0;
    ushort_t* xgb   = (ushort_t*)(wsb + off); off += 67108864;
    ushort_t* hb16  = (ushort_t*)(wsb + off); off += 16777216;
    float*    hlast = (float*)(wsb + off);    off += 262144;
    ushort_t* w1b   = (ushort_t*)(wsb + off);
    ushort_t* w2b   = w1b + (size_t)256 * D_INP;
    ushort_t* w3b   = w2b + (size_t)512 * 64;

    const int T = T_SZ;

    // weight conversions (tiny)
    convert_pad<<<208, 256, 0, stream>>>(wih1, w1b, D_IN, D_INP,
                                         (long)256 * (D_INP / 8));
    convert_pad<<<16, 256, 0, stream>>>(wih2, w2b, 64, 64, (long)512 * 8);
    convert_pad<<<16, 256, 0, stream>>>(wih3, w3b, 128, 128, (long)256 * 16);

    // Layer 1 (A read once: full-G tile)
    gemm_l1<<<M_SZ / 128, 512, 0, stream>>>(x, w1b, xgb);
    lstm_fused<64><<<B_SZ / 16, 256, 0, stream>>>(
        xgb, whh1, bih1, bhh1, hb16, nullptr, T);

    // Layer 2
    gemm_b16<<<dim3(4, M_SZ / 128), 256, 0, stream>>>(
        hb16, w2b, xgb, 64, 512);
    lstm_fused<128><<<B_SZ / 16, 512, 0, stream>>>(
        xgb, whh2, bih2, bhh2, hb16, nullptr, T);

    // Layer 3
    gemm_b16<<<dim3(2, M_SZ / 128), 256, 0, stream>>>(
        hb16, w3b, xgb, 128, 256);
    lstm_fused<64><<<B_SZ / 16, 256, 0, stream>>>(
        xgb, whh3, bih3, bhh3, nullptr, hlast, T);

    // Head
    head_kernel<<<B_SZ / 16, 256, 0, stream>>>(
        hlast, f1w, f1b, f2w, f2b, f3w, f3b, outp);
}

// Round 7
// 486.947 us; speedup vs baseline: 3.7751x; 1.0607x over previous
//
#include <hip/hip_runtime.h>
#include <hip/hip_bf16.h>

#define B_SZ   1024
#define T_SZ   64
#define D_IN   1662
#define D_INP  1664                 // padded to 32-multiple
#define M_SZ   (B_SZ * T_SZ)        // 65536

typedef __attribute__((ext_vector_type(8))) short short8;
typedef __attribute__((ext_vector_type(4))) float f32x4;
typedef unsigned short ushort_t;

// fp32 -> bf16 round-to-nearest-even (finite inputs)
__device__ __forceinline__ unsigned short f2bf(float f) {
    unsigned u = __builtin_bit_cast(unsigned, f);
    u += 0x7FFFu + ((u >> 16) & 1u);
    return (unsigned short)(u >> 16);
}
__device__ __forceinline__ float bf2f(ushort_t u) {
    return __builtin_bit_cast(float, (unsigned)u << 16);
}

// async global->LDS, 16B per lane, dest = wave-uniform base + lane*16
#define GLD16(gp, lp) __builtin_amdgcn_global_load_lds(                        \
    (const __attribute__((address_space(1))) void*)(gp),                       \
    (__attribute__((address_space(3))) void*)(lp), 16, 0, 0)

__device__ __forceinline__ float sigmoid_f(float x) {
    return 1.0f / (1.0f + __expf(-x));
}
__device__ __forceinline__ float tanh_f(float x) {
    float a = fabsf(x);
    float e = __expf(2.0f * a);
    float r = 1.0f - 2.0f / (e + 1.0f);
    return copysignf(r, x);
}

// ---------------------------------------------------------------------------
// convert fp32 [R,K] -> bf16 [R,Kp], zero-padding columns K..Kp. (weights only)
// ---------------------------------------------------------------------------
__global__ __launch_bounds__(256) void convert_pad(
    const float* __restrict__ src, ushort_t* __restrict__ dst,
    int K, int Kp, long total_chunks)
{
    const int cpr = Kp >> 3;
    const long stride = (long)gridDim.x * blockDim.x;
    for (long idx = (long)blockIdx.x * blockDim.x + threadIdx.x;
         idx < total_chunks; idx += stride) {
        const int row  = (int)(idx / cpr);
        const int base = ((int)(idx % cpr)) << 3;
        const float* s = src + (size_t)row * K;
        short8 o;
        #pragma unroll
        for (int j = 0; j < 4; ++j) {
            const int k = base + 2 * j;
            float2 v = make_float2(0.f, 0.f);
            if (k < K) v = *(const float2*)(s + k);
            o[2 * j]     = (short)f2bf(v.x);
            o[2 * j + 1] = (short)f2bf(v.y);
        }
        *(short8*)(dst + (size_t)row * Kp + base) = o;
    }
}

// ---------------------------------------------------------------------------
// Layer-1 GEMM: out[M,256]bf16 = A[M,K]fp32 @ W[256,Kp]bf16^T.
// 64x256 tile, BK=32, 256 threads (4 waves, 1x4), grid M/64=1024 ->
// 4 blocks/CU for TLP latency hiding. A read once (full-G tile).
// A: reg-staged fp32->bf16, prefetch for it+1 issued AFTER staging barrier
// (hides under MFMA). W: 4x global_load_lds width-16 per wave.
// ---------------------------------------------------------------------------
__global__ __launch_bounds__(256, 4) void gemm_l1(
    const float* __restrict__ A, const ushort_t* __restrict__ W,
    ushort_t* __restrict__ out)
{
    constexpr int K = D_IN, Kp = D_INP, G = 256;
    __shared__ __align__(16) ushort_t As[64 * 32];     //  4 KB
    __shared__ __align__(16) ushort_t Ws[256 * 32];    // 16 KB

    const int tid = threadIdx.x, lane = tid & 63, wid = tid >> 6;
    const int m0 = blockIdx.x * 64;

    // A staging: row tid>>2 (0..63), 8 fp32 at col (tid&3)*8 (float2-aligned)
    const int arow  = tid >> 2;
    const int acolb = (tid & 3) * 8;
    const float* Abase = A + (size_t)(m0 + arow) * K + acolb;

    // W staging: wave wid covers rows wid*64..+63 in 4 chunks of 16 rows
    const size_t wlofs = (size_t)(lane >> 2) * Kp + (lane & 3) * 8;
    const ushort_t* Wg0 = W + (size_t)(wid * 64) * Kp + wlofs;
    const ushort_t* Wg1 = Wg0 + (size_t)16 * Kp;
    const ushort_t* Wg2 = Wg0 + (size_t)32 * Kp;
    const ushort_t* Wg3 = Wg0 + (size_t)48 * Kp;
    ushort_t* lw0 = &Ws[(wid * 64) * 32];
    ushort_t* lw1 = lw0 + 16 * 32;
    ushort_t* lw2 = lw0 + 32 * 32;
    ushort_t* lw3 = lw0 + 48 * 32;

    const int fr = lane & 15, kq = (lane >> 4) * 8;

    f32x4 acc[4][4] = {};
    const int nFull = K / 32;                 // 51 full iters + 1 tail

    // prologue: A regs for it=0
    float2 av[4];
    #pragma unroll
    for (int j = 0; j < 4; ++j) av[j] = *(const float2*)(Abase + 2 * j);

    for (int it = 0; it <= nFull; ++it) {
        const int k0 = it * 32;
        __syncthreads();                      // prev iter LDS reads done
        GLD16(Wg0 + k0, lw0); GLD16(Wg1 + k0, lw1);
        GLD16(Wg2 + k0, lw2); GLD16(Wg3 + k0, lw3);
        short8 pk;
        #pragma unroll
        for (int j = 0; j < 4; ++j) {
            pk[2 * j]     = (short)f2bf(av[j].x);
            pk[2 * j + 1] = (short)f2bf(av[j].y);
        }
        *(short8*)&As[arow * 32 + acolb] = pk;
        __syncthreads();                      // staging (incl. vmcnt) done

        // prefetch A for it+1 (latency hides under MFMA below)
        if (it < nFull) {
            const int kn = (it + 1) * 32;
            if (it + 1 < nFull) {
                #pragma unroll
                for (int j = 0; j < 4; ++j)
                    av[j] = *(const float2*)(Abase + kn + 2 * j);
            } else {
                #pragma unroll
                for (int j = 0; j < 4; ++j) {
                    const int kk = kn + acolb + 2 * j;
                    av[j] = (kk < K) ? *(const float2*)(Abase + kn + 2 * j)
                                     : make_float2(0.f, 0.f);
                }
            }
        }

        short8 af[4], bfr[4];
        #pragma unroll
        for (int fm = 0; fm < 4; ++fm)
            af[fm] = *(const short8*)&As[(fm * 16 + fr) * 32 + kq];
        #pragma unroll
        for (int fn = 0; fn < 4; ++fn)
            bfr[fn] = *(const short8*)&Ws[(wid * 64 + fn * 16 + fr) * 32 + kq];
        #pragma unroll
        for (int fm = 0; fm < 4; ++fm)
            #pragma unroll
            for (int fn = 0; fn < 4; ++fn)
                acc[fm][fn] = __builtin_amdgcn_mfma_f32_16x16x32_bf16(
                    af[fm], bfr[fn], acc[fm][fn], 0, 0, 0);
    }

    // epilogue: bf16, no bias. C/D: col=lane&15, row=(lane>>4)*4+j
    const int rbase = (lane >> 4) * 4;
    #pragma unroll
    for (int fn = 0; fn < 4; ++fn) {
        const int g = wid * 64 + fn * 16 + fr;
        #pragma unroll
        for (int fm = 0; fm < 4; ++fm) {
            const int mbase = m0 + fm * 16 + rbase;
            #pragma unroll
            for (int j = 0; j < 4; ++j)
                out[(size_t)(mbase + j) * G + g] = f2bf(acc[fm][fn][j]);
        }
    }
}

// ---------------------------------------------------------------------------
// Layers 2/3 GEMM: out[M,G]bf16 = A[M,Kp]bf16 @ W[G,Kp]bf16^T (no bias).
// m97 structure, 128x128 tile, BK=32, GLD16 staging both operands.
// ---------------------------------------------------------------------------
__global__ __launch_bounds__(256) void gemm_b16(
    const ushort_t* __restrict__ A, const ushort_t* __restrict__ W,
    ushort_t* __restrict__ out, int Kp, int G)
{
    __shared__ __align__(16) ushort_t As[128 * 32];
    __shared__ __align__(16) ushort_t Ws[128 * 32];

    const int tid = threadIdx.x, lane = tid & 63, wid = tid >> 6;
    const int wr = wid >> 1, wc = wid & 1;
    const int m0 = blockIdx.y * 128, g0 = blockIdx.x * 128;

    const int srow = wid * 32 + (lane >> 2);
    const int skel = (lane & 3) * 8;
    const ushort_t* Ag  = A + (size_t)(m0 + srow) * Kp + skel;
    const ushort_t* Ag2 = Ag + (size_t)16 * Kp;
    const ushort_t* Wg  = W + (size_t)(g0 + srow) * Kp + skel;
    const ushort_t* Wg2 = Wg + (size_t)16 * Kp;

    ushort_t* la0 = &As[wid * 1024];
    ushort_t* la1 = la0 + 512;
    ushort_t* lw0 = &Ws[wid * 1024];
    ushort_t* lw1 = lw0 + 512;

    const int fr = lane & 15;
    const int kq = (lane >> 4) * 8;

    f32x4 acc[4][4] = {};

    for (int k0 = 0; k0 < Kp; k0 += 32) {
        __syncthreads();
        GLD16(Ag, la0);  GLD16(Ag2, la1);
        GLD16(Wg, lw0);  GLD16(Wg2, lw1);
        Ag += 32; Ag2 += 32; Wg += 32; Wg2 += 32;
        __syncthreads();

        short8 af[4], bfr[4];
        #pragma unroll
        for (int fm = 0; fm < 4; ++fm)
            af[fm] = *(const short8*)&As[(wr * 64 + fm * 16 + fr) * 32 + kq];
        #pragma unroll
        for (int fn = 0; fn < 4; ++fn)
            bfr[fn] = *(const short8*)&Ws[(wc * 64 + fn * 16 + fr) * 32 + kq];

        #pragma unroll
        for (int fm = 0; fm < 4; ++fm)
            #pragma unroll
            for (int fn = 0; fn < 4; ++fn)
                acc[fm][fn] = __builtin_amdgcn_mfma_f32_16x16x32_bf16(
                    af[fm], bfr[fn], acc[fm][fn], 0, 0, 0);
    }

    const int rbase = (lane >> 4) * 4;
    #pragma unroll
    for (int fn = 0; fn < 4; ++fn) {
        const int g = g0 + wc * 64 + fn * 16 + fr;
        #pragma unroll
        for (int fm = 0; fm < 4; ++fm) {
            const int mbase = m0 + wr * 64 + fm * 16 + rbase;
            #pragma unroll
            for (int j = 0; j < 4; ++j)
                out[(size_t)(mbase + j) * G + g] = f2bf(acc[fm][fn][j]);
        }
    }
}

// ---------------------------------------------------------------------------
// Gate-grouped MFMA LSTM, 1 barrier/step. 16 batch rows/block, 4H threads.
// Wave wid computes all four gates of units wid*16..+15 ({i,f,g,o} of one
// unit land in one lane's acc regs -> no gate-LDS round trip).
// h AND the xg tile are double-buffered in LDS; xg staged cooperatively
// (2x16B coalesced loads/thread/step, issued at step top).
// ---------------------------------------------------------------------------
template<int H, bool WH, bool WL>
__global__ __launch_bounds__(4 * H, 1) void lstm_fused(
    const ushort_t* __restrict__ xg,  // [B,T,4H] bf16, matmul only (no bias)
    const float* __restrict__ whh,    // [4H,H] fp32
    const float* __restrict__ bih, const float* __restrict__ bhh,
    ushort_t* __restrict__ hout16,    // [B,T,H] bf16 (if WH)
    float* __restrict__ hlast,        // [B,H] fp32 (if WL)
    int Tn)
{
    constexpr int G4  = 4 * H;
    constexpr int KS  = H / 32;
    constexpr int NT  = 4 * H;
    constexpr int XS  = G4 + 8;          // padded xbuf row stride (banks)
    constexpr int CPT = G4 / 16;         // loader threads per row

    __shared__ ushort_t hsh[2][16 * H];
    __shared__ ushort_t xbuf[2][16 * XS];

    const int tid = threadIdx.x, lane = tid & 63, wid = tid >> 6;
    const int r0 = blockIdx.x * 16;
    const int fr = lane & 15, kq = (lane >> 4) * 8;
    const int u = wid * 16 + fr;              // this lane's unit
    const int rbase = (lane >> 4) * 4;        // this lane's row base
    const int xrow = tid / CPT;               // cooperative xg loader mapping
    const int xcol = (tid % CPT) * 16;

    // B fragments: column (g*H + u) of whh^T, K-slice ks*32+kq
    short8 breg[4][KS];
    #pragma unroll
    for (int g = 0; g < 4; ++g)
        #pragma unroll
        for (int ks = 0; ks < KS; ++ks) {
            const float* wp = whh + (size_t)(g * H + u) * H + ks * 32 + kq;
            short8 b;
            #pragma unroll
            for (int j = 0; j < 8; ++j) b[j] = (short)f2bf(wp[j]);
            breg[g][ks] = b;
        }

    float bias[4];
    #pragma unroll
    for (int g = 0; g < 4; ++g) bias[g] = bih[g * H + u] + bhh[g * H + u];

    // init: zero h, stage xg(t=0)
    for (int i = tid; i < 16 * H; i += NT) hsh[0][i] = 0;
    {
        const ushort_t* p = xg + ((size_t)(r0 + xrow) * Tn) * G4 + xcol;
        *(short8*)&xbuf[0][xrow * XS + xcol]     = *(const short8*)p;
        *(short8*)&xbuf[0][xrow * XS + xcol + 8] = *(const short8*)(p + 8);
    }
    float c[4] = {0.f, 0.f, 0.f, 0.f};
    __syncthreads();

    int cur = 0;
    for (int t = 0; t < Tn; ++t) {
        const int nxt = cur ^ 1;

        // issue next step's xg loads (hide under this whole step)
        short8 xr0, xr1;
        if (t + 1 < Tn) {
            const ushort_t* p =
                xg + ((size_t)(r0 + xrow) * Tn + (t + 1)) * G4 + xcol;
            xr0 = *(const short8*)p;
            xr1 = *(const short8*)(p + 8);
        }

        // A-fragments (h) from swizzled LDS buffer cur
        short8 a[KS];
        #pragma unroll
        for (int ks = 0; ks < KS; ++ks) {
            const int k0 = ks * 32 + kq;
            a[ks] = *(const short8*)&hsh[cur][fr * H + (k0 ^ ((fr & 7) << 3))];
        }

        f32x4 acc[4] = {};
        #pragma unroll
        for (int g = 0; g < 4; ++g)
            #pragma unroll
            for (int ks = 0; ks < KS; ++ks)
                acc[g] = __builtin_amdgcn_mfma_f32_16x16x32_bf16(
                    a[ks], breg[g][ks], acc[g], 0, 0, 0);

        // cell update in-register (C/D: col=lane&15=unit, row=rbase+j)
        #pragma unroll
        for (int j = 0; j < 4; ++j) {
            const int row = rbase + j;
            const ushort_t* xb = &xbuf[cur][row * XS + u];
            const float gi = acc[0][j] + bf2f(xb[0])     + bias[0];
            const float gf = acc[1][j] + bf2f(xb[H])     + bias[1];
            const float gg = acc[2][j] + bf2f(xb[2 * H]) + bias[2];
            const float go = acc[3][j] + bf2f(xb[3 * H]) + bias[3];
            const float iv = sigmoid_f(gi);
            const float fv = sigmoid_f(gf);
            const float gv = tanh_f(gg);
            const float ov = sigmoid_f(go);
            c[j] = fmaf(fv, c[j], iv * gv);
            const float h = ov * tanh_f(c[j]);
            const ushort_t hb = f2bf(h);
            hsh[nxt][row * H + (u ^ ((row & 7) << 3))] = hb;
            if (WH)
                hout16[((size_t)(r0 + row) * Tn + t) * H + u] = hb;
            if (WL && t == Tn - 1)
                hlast[(size_t)(r0 + row) * H + u] = h;
        }

        // stage next xg tile
        if (t + 1 < Tn) {
            *(short8*)&xbuf[nxt][xrow * XS + xcol]     = xr0;
            *(short8*)&xbuf[nxt][xrow * XS + xcol + 8] = xr1;
        }
        __syncthreads();        // h(t) and xg(t+1) visible; WAR safe via ping-pong
        cur = nxt;
    }
}

// ---------------------------------------------------------------------------
// FC head: hlast[B,64] -> fc1 relu -> fc2 relu -> fc3 -> softmax
// ---------------------------------------------------------------------------
__global__ __launch_bounds__(256) void head_kernel(
    const float* __restrict__ hlast,
    const float* __restrict__ w1, const float* __restrict__ b1,
    const float* __restrict__ w2, const float* __restrict__ b2,
    const float* __restrict__ w3, const float* __restrict__ b3,
    float* __restrict__ out)
{
    __shared__ float W1[64][64];
    __shared__ float W2[32][64];
    __shared__ float W3[3][32];
    __shared__ float hin[16][64];
    __shared__ float a1[16][64];
    __shared__ float a2[16][32];
    __shared__ float lg[16][3];

    const int tid = threadIdx.x;
    const int r0 = blockIdx.x * 16;

    for (int i = tid; i < 64 * 64; i += 256) W1[i >> 6][i & 63] = w1[i];
    for (int i = tid; i < 32 * 64; i += 256) W2[i >> 6][i & 63] = w2[i];
    for (int i = tid; i < 3 * 32; i += 256) W3[i >> 5][i & 31] = w3[i];
    for (int i = tid; i < 16 * 64; i += 256) {
        int r = i >> 6, u = i & 63;
        hin[r][u] = hlast[(size_t)(r0 + r) * 64 + u];
    }
    __syncthreads();

    for (int i = tid; i < 16 * 64; i += 256) {
        int r = i >> 6, j = i & 63;
        float s = b1[j];
        #pragma unroll
        for (int k = 0; k < 64; ++k) s = fmaf(hin[r][k], W1[j][k], s);
        a1[r][j] = fmaxf(s, 0.f);
    }
    __syncthreads();

    for (int i = tid; i < 16 * 32; i += 256) {
        int r = i >> 5, j = i & 31;
        float s = b2[j];
        #pragma unroll
        for (int k = 0; k < 64; ++k) s = fmaf(a1[r][k], W2[j][k], s);
        a2[r][j] = fmaxf(s, 0.f);
    }
    __syncthreads();

    for (int i = tid; i < 16 * 3; i += 256) {
        int r = i / 3, j = i % 3;
        float s = b3[j];
        #pragma unroll
        for (int k = 0; k < 32; ++k) s = fmaf(a2[r][k], W3[j][k], s);
        lg[r][j] = s;
    }
    __syncthreads();

    if (tid < 16) {
        float l0 = lg[tid][0], l1 = lg[tid][1], l2 = lg[tid][2];
        float m = fmaxf(l0, fmaxf(l1, l2));
        float e0 = __expf(l0 - m), e1 = __expf(l1 - m), e2 = __expf(l2 - m);
        float inv = 1.0f / (e0 + e1 + e2);
        out[(size_t)(r0 + tid) * 3 + 0] = e0 * inv;
        out[(size_t)(r0 + tid) * 3 + 1] = e1 * inv;
        out[(size_t)(r0 + tid) * 3 + 2] = e2 * inv;
    }
}

// ---------------------------------------------------------------------------
extern "C" void kernel_launch(void* const* d_in, const int* in_sizes, int n_in,
                              void* d_out, int out_size, void* d_ws, size_t ws_size,
                              hipStream_t stream)
{
    const float* x    = (const float*)d_in[0];
    const float* wih1 = (const float*)d_in[1];
    const float* whh1 = (const float*)d_in[2];
    const float* bih1 = (const float*)d_in[3];
    const float* bhh1 = (const float*)d_in[4];
    const float* wih2 = (const float*)d_in[5];
    const float* whh2 = (const float*)d_in[6];
    const float* bih2 = (const float*)d_in[7];
    const float* bhh2 = (const float*)d_in[8];
    const float* wih3 = (const float*)d_in[9];
    const float* whh3 = (const float*)d_in[10];
    const float* bih3 = (const float*)d_in[11];
    const float* bhh3 = (const float*)d_in[12];
    const float* f1w  = (const float*)d_in[13];
    const float* f1b  = (const float*)d_in[14];
    const float* f2w  = (const float*)d_in[15];
    const float* f2b  = (const float*)d_in[16];
    const float* f3w  = (const float*)d_in[17];
    const float* f3b  = (const float*)d_in[18];
    float* outp = (float*)d_out;

    // workspace layout (~85 MB):
    //   xgb   : 67,108,864 B  (bf16 [M,512] max; shared by layers 1/2/3)
    //   hb16  : 16,777,216 B  (bf16 [M,128] max)
    //   hlast :    262,144 B  (fp32 [B,64])
    //   w1b/w2b/w3b : bf16 weights (~1 MB)
    char* wsb = (char*)d_ws;
    size_t off = 0;
    ushort_t* xgb   = (ushort_t*)(wsb + off); off += 67108864;
    ushort_t* hb16  = (ushort_t*)(wsb + off); off += 16777216;
    float*    hlast = (float*)(wsb + off);    off += 262144;
    ushort_t* w1b   = (ushort_t*)(wsb + off);
    ushort_t* w2b   = w1b + (size_t)256 * D_INP;
    ushort_t* w3b   = w2b + (size_t)512 * 64;

    const int T = T_SZ;

    // weight conversions (tiny)
    convert_pad<<<208, 256, 0, stream>>>(wih1, w1b, D_IN, D_INP,
                                         (long)256 * (D_INP / 8));
    convert_pad<<<16, 256, 0, stream>>>(wih2, w2b, 64, 64, (long)512 * 8);
    convert_pad<<<16, 256, 0, stream>>>(wih3, w3b, 128, 128, (long)256 * 16);

    // Layer 1 (A read once; 4 blocks/CU)
    gemm_l1<<<M_SZ / 64, 256, 0, stream>>>(x, w1b, xgb);
    lstm_fused<64, true, false><<<B_SZ / 16, 256, 0, stream>>>(
        xgb, whh1, bih1, bhh1, hb16, nullptr, T);

    // Layer 2
    gemm_b16<<<dim3(4, M_SZ / 128), 256, 0, stream>>>(
        hb16, w2b, xgb, 64, 512);
    lstm_fused<128, true, false><<<B_SZ / 16, 512, 0, stream>>>(
        xgb, whh2, bih2, bhh2, hb16, nullptr, T);

    // Layer 3
    gemm_b16<<<dim3(2, M_SZ / 128), 256, 0, stream>>>(
        hb16, w3b, xgb, 128, 256);
    lstm_fused<64, false, true><<<B_SZ / 16, 256, 0, stream>>>(
        xgb, whh3, bih3, bhh3, nullptr, hlast, T);

    // Head
    head_kernel<<<B_SZ / 16, 256, 0, stream>>>(
        hlast, f1w, f1b, f2w, f2b, f3w, f3b, outp);
}

// Round 8
// 479.757 us; speedup vs baseline: 3.8316x; 1.0150x over previous
//
#include <hip/hip_runtime.h>
#include <hip/hip_bf16.h>

#define B_SZ   1024
#define T_SZ   64
#define D_IN   1662
#define D_INP  1664                 // padded to 32-multiple
#define M_SZ   (B_SZ * T_SZ)        // 65536

typedef __attribute__((ext_vector_type(8))) short short8;
typedef __attribute__((ext_vector_type(4))) float f32x4;
typedef unsigned short ushort_t;

// fp32 -> bf16 round-to-nearest-even (finite inputs)
__device__ __forceinline__ unsigned short f2bf(float f) {
    unsigned u = __builtin_bit_cast(unsigned, f);
    u += 0x7FFFu + ((u >> 16) & 1u);
    return (unsigned short)(u >> 16);
}
__device__ __forceinline__ float bf2f(ushort_t u) {
    return __builtin_bit_cast(float, (unsigned)u << 16);
}

// async global->LDS, 16B per lane, dest = wave-uniform base + lane*16
#define GLD16(gp, lp) __builtin_amdgcn_global_load_lds(                        \
    (const __attribute__((address_space(1))) void*)(gp),                       \
    (__attribute__((address_space(3))) void*)(lp), 16, 0, 0)

__device__ __forceinline__ float sigmoid_f(float x) {
    return 1.0f / (1.0f + __expf(-x));
}
__device__ __forceinline__ float tanh_f(float x) {
    float a = fabsf(x);
    float e = __expf(2.0f * a);
    float r = 1.0f - 2.0f / (e + 1.0f);
    return copysignf(r, x);
}

// ---------------------------------------------------------------------------
// One-shot weight conversion: w1 [256,1662]->[256,1664], w2 [512,64],
// w3 [256,128]. Flat chunk index over all three (8 bf16 per chunk).
// ---------------------------------------------------------------------------
__global__ __launch_bounds__(256) void convert_weights(
    const float* __restrict__ w1, const float* __restrict__ w2,
    const float* __restrict__ w3,
    ushort_t* __restrict__ d1, ushort_t* __restrict__ d2,
    ushort_t* __restrict__ d3)
{
    constexpr int C1 = 256 * (D_INP / 8);      // 53248
    constexpr int C2 = 512 * (64 / 8);         // 4096
    constexpr int C3 = 256 * (128 / 8);        // 4096
    const int stride = gridDim.x * blockDim.x;
    for (int idx = blockIdx.x * blockDim.x + threadIdx.x;
         idx < C1 + C2 + C3; idx += stride) {
        const float* src; ushort_t* dst; int K, Kp, ci;
        if (idx < C1)            { src = w1; dst = d1; K = D_IN; Kp = D_INP; ci = idx; }
        else if (idx < C1 + C2)  { src = w2; dst = d2; K = 64;   Kp = 64;   ci = idx - C1; }
        else                     { src = w3; dst = d3; K = 128;  Kp = 128;  ci = idx - C1 - C2; }
        const int cpr  = Kp >> 3;
        const int row  = ci / cpr;
        const int base = (ci % cpr) << 3;
        const float* s = src + (size_t)row * K;
        short8 o;
        #pragma unroll
        for (int j = 0; j < 4; ++j) {
            const int k = base + 2 * j;
            float2 v = make_float2(0.f, 0.f);
            if (k < K) v = *(const float2*)(s + k);
            o[2 * j]     = (short)f2bf(v.x);
            o[2 * j + 1] = (short)f2bf(v.y);
        }
        *(short8*)(dst + (size_t)row * Kp + base) = o;
    }
}

// ---------------------------------------------------------------------------
// Layer-1 GEMM: out[M,256]bf16 = A[M,K]fp32 @ W[256,Kp]bf16^T.
// 64x256 tile, BK=32, 256 threads (4 waves), grid M/64=1024 -> 4 blocks/CU.
// ---------------------------------------------------------------------------
__global__ __launch_bounds__(256, 4) void gemm_l1(
    const float* __restrict__ A, const ushort_t* __restrict__ W,
    ushort_t* __restrict__ out)
{
    constexpr int K = D_IN, Kp = D_INP, G = 256;
    __shared__ __align__(16) ushort_t As[64 * 32];     //  4 KB
    __shared__ __align__(16) ushort_t Ws[256 * 32];    // 16 KB

    const int tid = threadIdx.x, lane = tid & 63, wid = tid >> 6;
    const int m0 = blockIdx.x * 64;

    const int arow  = tid >> 2;
    const int acolb = (tid & 3) * 8;
    const float* Abase = A + (size_t)(m0 + arow) * K + acolb;

    const size_t wlofs = (size_t)(lane >> 2) * Kp + (lane & 3) * 8;
    const ushort_t* Wg0 = W + (size_t)(wid * 64) * Kp + wlofs;
    const ushort_t* Wg1 = Wg0 + (size_t)16 * Kp;
    const ushort_t* Wg2 = Wg0 + (size_t)32 * Kp;
    const ushort_t* Wg3 = Wg0 + (size_t)48 * Kp;
    ushort_t* lw0 = &Ws[(wid * 64) * 32];
    ushort_t* lw1 = lw0 + 16 * 32;
    ushort_t* lw2 = lw0 + 32 * 32;
    ushort_t* lw3 = lw0 + 48 * 32;

    const int fr = lane & 15, kq = (lane >> 4) * 8;

    f32x4 acc[4][4] = {};
    const int nFull = K / 32;                 // 51 full iters + 1 tail

    float2 av[4];
    #pragma unroll
    for (int j = 0; j < 4; ++j) av[j] = *(const float2*)(Abase + 2 * j);

    for (int it = 0; it <= nFull; ++it) {
        const int k0 = it * 32;
        __syncthreads();
        GLD16(Wg0 + k0, lw0); GLD16(Wg1 + k0, lw1);
        GLD16(Wg2 + k0, lw2); GLD16(Wg3 + k0, lw3);
        short8 pk;
        #pragma unroll
        for (int j = 0; j < 4; ++j) {
            pk[2 * j]     = (short)f2bf(av[j].x);
            pk[2 * j + 1] = (short)f2bf(av[j].y);
        }
        *(short8*)&As[arow * 32 + acolb] = pk;
        __syncthreads();

        if (it < nFull) {
            const int kn = (it + 1) * 32;
            if (it + 1 < nFull) {
                #pragma unroll
                for (int j = 0; j < 4; ++j)
                    av[j] = *(const float2*)(Abase + kn + 2 * j);
            } else {
                #pragma unroll
                for (int j = 0; j < 4; ++j) {
                    const int kk = kn + acolb + 2 * j;
                    av[j] = (kk < K) ? *(const float2*)(Abase + kn + 2 * j)
                                     : make_float2(0.f, 0.f);
                }
            }
        }

        short8 af[4], bfr[4];
        #pragma unroll
        for (int fm = 0; fm < 4; ++fm)
            af[fm] = *(const short8*)&As[(fm * 16 + fr) * 32 + kq];
        #pragma unroll
        for (int fn = 0; fn < 4; ++fn)
            bfr[fn] = *(const short8*)&Ws[(wid * 64 + fn * 16 + fr) * 32 + kq];
        #pragma unroll
        for (int fm = 0; fm < 4; ++fm)
            #pragma unroll
            for (int fn = 0; fn < 4; ++fn)
                acc[fm][fn] = __builtin_amdgcn_mfma_f32_16x16x32_bf16(
                    af[fm], bfr[fn], acc[fm][fn], 0, 0, 0);
    }

    const int rbase = (lane >> 4) * 4;
    #pragma unroll
    for (int fn = 0; fn < 4; ++fn) {
        const int g = wid * 64 + fn * 16 + fr;
        #pragma unroll
        for (int fm = 0; fm < 4; ++fm) {
            const int mbase = m0 + fm * 16 + rbase;
            #pragma unroll
            for (int j = 0; j < 4; ++j)
                out[(size_t)(mbase + j) * G + g] = f2bf(acc[fm][fn][j]);
        }
    }
}

// ---------------------------------------------------------------------------
// Gate-grouped MFMA LSTM with FUSED next-layer input GEMM.
// 16 batch rows/block, 4H threads. Wave wid owns units wid*16..+15 (all 4
// gates in-register). Per step t: a = h(t-1) fragments are used BOTH for the
// recurrence (breg1) and for xg_next(t-1) = h(t-1) @ wnext^T (breg2, stores
// overlap the step). Tail emits xg_next(T-1). GN=0 disables fusion.
// ---------------------------------------------------------------------------
template<int H, int GN, bool WL>
__global__ __launch_bounds__(4 * H, 1) void lstm_fused(
    const ushort_t* __restrict__ xg,    // [B,T,4H] bf16 (no bias)
    const float* __restrict__ whh,      // [4H,H] fp32
    const float* __restrict__ bih, const float* __restrict__ bhh,
    const ushort_t* __restrict__ wnext, // [GN,H] bf16 (if GN>0)
    ushort_t* __restrict__ xgnext,      // [B,T,GN] bf16 (if GN>0)
    float* __restrict__ hlast,          // [B,H] fp32 (if WL)
    int Tn)
{
    constexpr int G4  = 4 * H;
    constexpr int KS  = H / 32;
    constexpr int NT  = 4 * H;
    constexpr int NW  = H / 16;               // waves
    constexpr int NTN = (GN > 0) ? GN / 16 / NW : 1;  // next-gemm ntiles/wave
    constexpr int XS  = G4 + 8;
    constexpr int CPT = G4 / 16;

    __shared__ ushort_t hsh[2][16 * H];
    __shared__ ushort_t xbuf[2][16 * XS];

    const int tid = threadIdx.x, lane = tid & 63, wid = tid >> 6;
    const int r0 = blockIdx.x * 16;
    const int fr = lane & 15, kq = (lane >> 4) * 8;
    const int u = wid * 16 + fr;
    const int rbase = (lane >> 4) * 4;
    const int xrow = tid / CPT;
    const int xcol = (tid % CPT) * 16;

    // recurrence B fragments
    short8 breg1[4][KS];
    #pragma unroll
    for (int g = 0; g < 4; ++g)
        #pragma unroll
        for (int ks = 0; ks < KS; ++ks) {
            const float* wp = whh + (size_t)(g * H + u) * H + ks * 32 + kq;
            short8 b;
            #pragma unroll
            for (int j = 0; j < 8; ++j) b[j] = (short)f2bf(wp[j]);
            breg1[g][ks] = b;
        }

    // fused next-layer B fragments (bf16 global, layout [GN][H])
    short8 breg2[NTN][KS];
    if (GN > 0) {
        #pragma unroll
        for (int nt = 0; nt < NTN; ++nt)
            #pragma unroll
            for (int ks = 0; ks < KS; ++ks) {
                const int cn = wid * (NTN * 16) + nt * 16 + fr;
                breg2[nt][ks] =
                    *(const short8*)(wnext + (size_t)cn * H + ks * 32 + kq);
            }
    }

    float bias[4];
    #pragma unroll
    for (int g = 0; g < 4; ++g) bias[g] = bih[g * H + u] + bhh[g * H + u];

    for (int i = tid; i < 16 * H; i += NT) hsh[0][i] = 0;
    {
        const ushort_t* p = xg + ((size_t)(r0 + xrow) * Tn) * G4 + xcol;
        *(short8*)&xbuf[0][xrow * XS + xcol]     = *(const short8*)p;
        *(short8*)&xbuf[0][xrow * XS + xcol + 8] = *(const short8*)(p + 8);
    }
    float c[4] = {0.f, 0.f, 0.f, 0.f};
    __syncthreads();

    int cur = 0;
    for (int t = 0; t < Tn; ++t) {
        const int nxt = cur ^ 1;

        // next step's xg (register prefetch; hides under this step)
        short8 xr0, xr1;
        if (t + 1 < Tn) {
            const ushort_t* p =
                xg + ((size_t)(r0 + xrow) * Tn + (t + 1)) * G4 + xcol;
            xr0 = *(const short8*)p;
            xr1 = *(const short8*)(p + 8);
        }

        // a = h(t-1) fragments
        short8 a[KS];
        #pragma unroll
        for (int ks = 0; ks < KS; ++ks) {
            const int k0 = ks * 32 + kq;
            a[ks] = *(const short8*)&hsh[cur][fr * H + (k0 ^ ((fr & 7) << 3))];
        }

        // recurrence MFMAs
        f32x4 acc1[4] = {};
        #pragma unroll
        for (int g = 0; g < 4; ++g)
            #pragma unroll
            for (int ks = 0; ks < KS; ++ks)
                acc1[g] = __builtin_amdgcn_mfma_f32_16x16x32_bf16(
                    a[ks], breg1[g][ks], acc1[g], 0, 0, 0);

        // fused next-layer GEMM for row time (t-1): xg_next = h(t-1) @ wnext^T
        if (GN > 0 && t > 0) {
            f32x4 acc2[NTN] = {};
            #pragma unroll
            for (int nt = 0; nt < NTN; ++nt)
                #pragma unroll
                for (int ks = 0; ks < KS; ++ks)
                    acc2[nt] = __builtin_amdgcn_mfma_f32_16x16x32_bf16(
                        a[ks], breg2[nt][ks], acc2[nt], 0, 0, 0);
            #pragma unroll
            for (int nt = 0; nt < NTN; ++nt) {
                const int cn = wid * (NTN * 16) + nt * 16 + fr;
                #pragma unroll
                for (int j = 0; j < 4; ++j)
                    xgnext[((size_t)(r0 + rbase + j) * Tn + (t - 1)) * GN + cn]
                        = f2bf(acc2[nt][j]);
            }
        }

        // cell update (in-register; C/D col=unit, row=rbase+j)
        #pragma unroll
        for (int j = 0; j < 4; ++j) {
            const int row = rbase + j;
            const ushort_t* xb = &xbuf[cur][row * XS + u];
            const float gi = acc1[0][j] + bf2f(xb[0])     + bias[0];
            const float gf = acc1[1][j] + bf2f(xb[H])     + bias[1];
            const float gg = acc1[2][j] + bf2f(xb[2 * H]) + bias[2];
            const float go = acc1[3][j] + bf2f(xb[3 * H]) + bias[3];
            const float iv = sigmoid_f(gi);
            const float fv = sigmoid_f(gf);
            const float gv = tanh_f(gg);
            const float ov = sigmoid_f(go);
            c[j] = fmaf(fv, c[j], iv * gv);
            const float h = ov * tanh_f(c[j]);
            hsh[nxt][row * H + (u ^ ((row & 7) << 3))] = f2bf(h);
            if (WL && t == Tn - 1)
                hlast[(size_t)(r0 + row) * H + u] = h;
        }

        if (t + 1 < Tn) {
            *(short8*)&xbuf[nxt][xrow * XS + xcol]     = xr0;
            *(short8*)&xbuf[nxt][xrow * XS + xcol + 8] = xr1;
        }
        __syncthreads();
        cur = nxt;
    }

    // tail: xg_next for t = T-1 from h(T-1) (now in hsh[cur])
    if (GN > 0) {
        short8 a[KS];
        #pragma unroll
        for (int ks = 0; ks < KS; ++ks) {
            const int k0 = ks * 32 + kq;
            a[ks] = *(const short8*)&hsh[cur][fr * H + (k0 ^ ((fr & 7) << 3))];
        }
        f32x4 acc2[NTN] = {};
        #pragma unroll
        for (int nt = 0; nt < NTN; ++nt)
            #pragma unroll
            for (int ks = 0; ks < KS; ++ks)
                acc2[nt] = __builtin_amdgcn_mfma_f32_16x16x32_bf16(
                    a[ks], breg2[nt][ks], acc2[nt], 0, 0, 0);
        #pragma unroll
        for (int nt = 0; nt < NTN; ++nt) {
            const int cn = wid * (NTN * 16) + nt * 16 + fr;
            #pragma unroll
            for (int j = 0; j < 4; ++j)
                xgnext[((size_t)(r0 + rbase + j) * Tn + (Tn - 1)) * GN + cn]
                    = f2bf(acc2[nt][j]);
        }
    }
}

// ---------------------------------------------------------------------------
// FC head: hlast[B,64] -> fc1 relu -> fc2 relu -> fc3 -> softmax
// ---------------------------------------------------------------------------
__global__ __launch_bounds__(256) void head_kernel(
    const float* __restrict__ hlast,
    const float* __restrict__ w1, const float* __restrict__ b1,
    const float* __restrict__ w2, const float* __restrict__ b2,
    const float* __restrict__ w3, const float* __restrict__ b3,
    float* __restrict__ out)
{
    __shared__ float W1[64][64];
    __shared__ float W2[32][64];
    __shared__ float W3[3][32];
    __shared__ float hin[16][64];
    __shared__ float a1[16][64];
    __shared__ float a2[16][32];
    __shared__ float lg[16][3];

    const int tid = threadIdx.x;
    const int r0 = blockIdx.x * 16;

    for (int i = tid; i < 64 * 64; i += 256) W1[i >> 6][i & 63] = w1[i];
    for (int i = tid; i < 32 * 64; i += 256) W2[i >> 6][i & 63] = w2[i];
    for (int i = tid; i < 3 * 32; i += 256) W3[i >> 5][i & 31] = w3[i];
    for (int i = tid; i < 16 * 64; i += 256) {
        int r = i >> 6, u = i & 63;
        hin[r][u] = hlast[(size_t)(r0 + r) * 64 + u];
    }
    __syncthreads();

    for (int i = tid; i < 16 * 64; i += 256) {
        int r = i >> 6, j = i & 63;
        float s = b1[j];
        #pragma unroll
        for (int k = 0; k < 64; ++k) s = fmaf(hin[r][k], W1[j][k], s);
        a1[r][j] = fmaxf(s, 0.f);
    }
    __syncthreads();

    for (int i = tid; i < 16 * 32; i += 256) {
        int r = i >> 5, j = i & 31;
        float s = b2[j];
        #pragma unroll
        for (int k = 0; k < 64; ++k) s = fmaf(a1[r][k], W2[j][k], s);
        a2[r][j] = fmaxf(s, 0.f);
    }
    __syncthreads();

    for (int i = tid; i < 16 * 3; i += 256) {
        int r = i / 3, j = i % 3;
        float s = b3[j];
        #pragma unroll
        for (int k = 0; k < 32; ++k) s = fmaf(a2[r][k], W3[j][k], s);
        lg[r][j] = s;
    }
    __syncthreads();

    if (tid < 16) {
        float l0 = lg[tid][0], l1 = lg[tid][1], l2 = lg[tid][2];
        float m = fmaxf(l0, fmaxf(l1, l2));
        float e0 = __expf(l0 - m), e1 = __expf(l1 - m), e2 = __expf(l2 - m);
        float inv = 1.0f / (e0 + e1 + e2);
        out[(size_t)(r0 + tid) * 3 + 0] = e0 * inv;
        out[(size_t)(r0 + tid) * 3 + 1] = e1 * inv;
        out[(size_t)(r0 + tid) * 3 + 2] = e2 * inv;
    }
}

// ---------------------------------------------------------------------------
extern "C" void kernel_launch(void* const* d_in, const int* in_sizes, int n_in,
                              void* d_out, int out_size, void* d_ws, size_t ws_size,
                              hipStream_t stream)
{
    const float* x    = (const float*)d_in[0];
    const float* wih1 = (const float*)d_in[1];
    const float* whh1 = (const float*)d_in[2];
    const float* bih1 = (const float*)d_in[3];
    const float* bhh1 = (const float*)d_in[4];
    const float* wih2 = (const float*)d_in[5];
    const float* whh2 = (const float*)d_in[6];
    const float* bih2 = (const float*)d_in[7];
    const float* bhh2 = (const float*)d_in[8];
    const float* wih3 = (const float*)d_in[9];
    const float* whh3 = (const float*)d_in[10];
    const float* bih3 = (const float*)d_in[11];
    const float* bhh3 = (const float*)d_in[12];
    const float* f1w  = (const float*)d_in[13];
    const float* f1b  = (const float*)d_in[14];
    const float* f2w  = (const float*)d_in[15];
    const float* f2b  = (const float*)d_in[16];
    const float* f3w  = (const float*)d_in[17];
    const float* f3b  = (const float*)d_in[18];
    float* outp = (float*)d_out;

    // workspace layout (~102 MB):
    //   bufA : 33,554,432 B  (bf16 [M,256]: xg1, later xg3)
    //   bufB : 67,108,864 B  (bf16 [M,512]: xg2)
    //   hlast:    262,144 B  (fp32 [B,64])
    //   w1b/w2b/w3b : bf16 weights (~1 MB)
    char* wsb = (char*)d_ws;
    size_t off = 0;
    ushort_t* bufA  = (ushort_t*)(wsb + off); off += 33554432;
    ushort_t* bufB  = (ushort_t*)(wsb + off); off += 67108864;
    float*    hlast = (float*)(wsb + off);    off += 262144;
    ushort_t* w1b   = (ushort_t*)(wsb + off);
    ushort_t* w2b   = w1b + (size_t)256 * D_INP;
    ushort_t* w3b   = w2b + (size_t)512 * 64;

    const int T = T_SZ;

    // all weight conversions in one dispatch
    convert_weights<<<240, 256, 0, stream>>>(wih1, wih2, wih3, w1b, w2b, w3b);

    // Layer 1 GEMM (x read once; 4 blocks/CU)
    gemm_l1<<<M_SZ / 64, 256, 0, stream>>>(x, w1b, bufA);

    // Layer 1 LSTM + fused GEMM2 -> xg2
    lstm_fused<64, 512, false><<<B_SZ / 16, 256, 0, stream>>>(
        bufA, whh1, bih1, bhh1, w2b, bufB, nullptr, T);

    // Layer 2 LSTM + fused GEMM3 -> xg3
    lstm_fused<128, 256, false><<<B_SZ / 16, 512, 0, stream>>>(
        bufB, whh2, bih2, bhh2, w3b, bufA, nullptr, T);

    // Layer 3 LSTM -> hlast
    lstm_fused<64, 0, true><<<B_SZ / 16, 256, 0, stream>>>(
        bufA, whh3, bih3, bhh3, nullptr, nullptr, hlast, T);

    // Head
    head_kernel<<<B_SZ / 16, 256, 0, stream>>>(
        hlast, f1w, f1b, f2w, f2b, f3w, f3b, outp);
}

// Round 9
// 371.675 us; speedup vs baseline: 4.9459x; 1.2908x over previous
//
#include <hip/hip_runtime.h>
#include <hip/hip_bf16.h>

#define B_SZ   1024
#define T_SZ   64
#define D_IN   1662
#define D_INP  1664                 // padded to 32-multiple
#define M_SZ   (B_SZ * T_SZ)        // 65536

typedef __attribute__((ext_vector_type(8))) short short8;
typedef __attribute__((ext_vector_type(4))) float f32x4;
typedef unsigned short ushort_t;

// fp32 -> bf16 round-to-nearest-even (finite inputs)
__device__ __forceinline__ unsigned short f2bf(float f) {
    unsigned u = __builtin_bit_cast(unsigned, f);
    u += 0x7FFFu + ((u >> 16) & 1u);
    return (unsigned short)(u >> 16);
}
__device__ __forceinline__ float bf2f(ushort_t u) {
    return __builtin_bit_cast(float, (unsigned)u << 16);
}

// async global->LDS, 16B per lane, dest = wave-uniform base + lane*16
#define GLD16(gp, lp) __builtin_amdgcn_global_load_lds(                        \
    (const __attribute__((address_space(1))) void*)(gp),                       \
    (__attribute__((address_space(3))) void*)(lp), 16, 0, 0)

__device__ __forceinline__ float sigmoid_f(float x) {
    return 1.0f / (1.0f + __expf(-x));
}
__device__ __forceinline__ float tanh_f(float x) {
    float a = fabsf(x);
    float e = __expf(2.0f * a);
    float r = 1.0f - 2.0f / (e + 1.0f);
    return copysignf(r, x);
}

// ---------------------------------------------------------------------------
// convert fp32 [256,1662] -> bf16 [256,1664] (w_ih1 only)
// ---------------------------------------------------------------------------
__global__ __launch_bounds__(256) void convert_w1(
    const float* __restrict__ src, ushort_t* __restrict__ dst)
{
    constexpr int cpr = D_INP >> 3;
    const int total = 256 * cpr;
    const int stride = gridDim.x * blockDim.x;
    for (int idx = blockIdx.x * blockDim.x + threadIdx.x;
         idx < total; idx += stride) {
        const int row  = idx / cpr;
        const int base = (idx % cpr) << 3;
        const float* s = src + (size_t)row * D_IN;
        short8 o;
        #pragma unroll
        for (int j = 0; j < 4; ++j) {
            const int k = base + 2 * j;
            float2 v = make_float2(0.f, 0.f);
            if (k < D_IN) v = *(const float2*)(s + k);
            o[2 * j]     = (short)f2bf(v.x);
            o[2 * j + 1] = (short)f2bf(v.y);
        }
        *(short8*)(dst + (size_t)row * D_INP + base) = o;
    }
}

// ---------------------------------------------------------------------------
// Layer-1 GEMM: out[M,256]bf16 = A[M,K]fp32 @ W[256,Kp]bf16^T.
// 64x256 tile, BK=32, 256 threads (4 waves), grid M/64=1024 -> 4 blocks/CU.
// ---------------------------------------------------------------------------
__global__ __launch_bounds__(256, 4) void gemm_l1(
    const float* __restrict__ A, const ushort_t* __restrict__ W,
    ushort_t* __restrict__ out)
{
    constexpr int K = D_IN, Kp = D_INP, G = 256;
    __shared__ __align__(16) ushort_t As[64 * 32];     //  4 KB
    __shared__ __align__(16) ushort_t Ws[256 * 32];    // 16 KB

    const int tid = threadIdx.x, lane = tid & 63, wid = tid >> 6;
    const int m0 = blockIdx.x * 64;

    const int arow  = tid >> 2;
    const int acolb = (tid & 3) * 8;
    const float* Abase = A + (size_t)(m0 + arow) * K + acolb;

    const size_t wlofs = (size_t)(lane >> 2) * Kp + (lane & 3) * 8;
    const ushort_t* Wg0 = W + (size_t)(wid * 64) * Kp + wlofs;
    const ushort_t* Wg1 = Wg0 + (size_t)16 * Kp;
    const ushort_t* Wg2 = Wg0 + (size_t)32 * Kp;
    const ushort_t* Wg3 = Wg0 + (size_t)48 * Kp;
    ushort_t* lw0 = &Ws[(wid * 64) * 32];
    ushort_t* lw1 = lw0 + 16 * 32;
    ushort_t* lw2 = lw0 + 32 * 32;
    ushort_t* lw3 = lw0 + 48 * 32;

    const int fr = lane & 15, kq = (lane >> 4) * 8;

    f32x4 acc[4][4] = {};
    const int nFull = K / 32;                 // 51 full iters + 1 tail

    float2 av[4];
    #pragma unroll
    for (int j = 0; j < 4; ++j) av[j] = *(const float2*)(Abase + 2 * j);

    for (int it = 0; it <= nFull; ++it) {
        const int k0 = it * 32;
        __syncthreads();
        GLD16(Wg0 + k0, lw0); GLD16(Wg1 + k0, lw1);
        GLD16(Wg2 + k0, lw2); GLD16(Wg3 + k0, lw3);
        short8 pk;
        #pragma unroll
        for (int j = 0; j < 4; ++j) {
            pk[2 * j]     = (short)f2bf(av[j].x);
            pk[2 * j + 1] = (short)f2bf(av[j].y);
        }
        *(short8*)&As[arow * 32 + acolb] = pk;
        __syncthreads();

        if (it < nFull) {
            const int kn = (it + 1) * 32;
            if (it + 1 < nFull) {
                #pragma unroll
                for (int j = 0; j < 4; ++j)
                    av[j] = *(const float2*)(Abase + kn + 2 * j);
            } else {
                #pragma unroll
                for (int j = 0; j < 4; ++j) {
                    const int kk = kn + acolb + 2 * j;
                    av[j] = (kk < K) ? *(const float2*)(Abase + kn + 2 * j)
                                     : make_float2(0.f, 0.f);
                }
            }
        }

        short8 af[4], bfr[4];
        #pragma unroll
        for (int fm = 0; fm < 4; ++fm)
            af[fm] = *(const short8*)&As[(fm * 16 + fr) * 32 + kq];
        #pragma unroll
        for (int fn = 0; fn < 4; ++fn)
            bfr[fn] = *(const short8*)&Ws[(wid * 64 + fn * 16 + fr) * 32 + kq];
        #pragma unroll
        for (int fm = 0; fm < 4; ++fm)
            #pragma unroll
            for (int fn = 0; fn < 4; ++fn)
                acc[fm][fn] = __builtin_amdgcn_mfma_f32_16x16x32_bf16(
                    af[fm], bfr[fn], acc[fm][fn], 0, 0, 0);
    }

    const int rbase = (lane >> 4) * 4;
    #pragma unroll
    for (int fn = 0; fn < 4; ++fn) {
        const int g = wid * 64 + fn * 16 + fr;
        #pragma unroll
        for (int fm = 0; fm < 4; ++fm) {
            const int mbase = m0 + fm * 16 + rbase;
            #pragma unroll
            for (int j = 0; j < 4; ++j)
                out[(size_t)(mbase + j) * G + g] = f2bf(acc[fm][fn][j]);
        }
    }
}

// ---------------------------------------------------------------------------
// Pipelined 3-layer LSTM. 256 blocks x 512 threads; 4 batch rows/block.
// Wave roles: wid 0-1 -> layer1 (H=64), 2-5 -> layer2 (H=128), 6-7 -> layer3.
// Step s: L1 computes h1(s); L2 computes h2(s-1) = f(h1(s-1), h2(s-2));
// L3 computes h3(s-2). 66 steps. All h state in double-buffered LDS
// (producers write buf (s+1)&1, consumers read buf s&1). Gates go through
// LDS once; cell update spread over all 512 threads (2 items each).
// xg2/xg3 never materialize in global memory.
// ---------------------------------------------------------------------------
__global__ __launch_bounds__(512, 2) void lstm3_pipe(
    const ushort_t* __restrict__ xg1,   // [B,T,256] bf16 (no bias)
    const float* __restrict__ whh1,
    const float* __restrict__ bih1, const float* __restrict__ bhh1,
    const float* __restrict__ wih2, const float* __restrict__ whh2,
    const float* __restrict__ bih2, const float* __restrict__ bhh2,
    const float* __restrict__ wih3, const float* __restrict__ whh3,
    const float* __restrict__ bih3, const float* __restrict__ bhh3,
    float* __restrict__ hlast, int Tn)  // [B,64]
{
    __shared__ ushort_t h1sh[2][16 * 64];
    __shared__ ushort_t h2sh[2][16 * 128];
    __shared__ ushort_t h3sh[2][16 * 64];
    __shared__ ushort_t xsh[2][4 * 256];
    __shared__ float    gsh[4][1024];    // gates, col = sec + g*Hl + u
    __shared__ float    bsh[1024];       // bias table, same col layout

    const int tid = threadIdx.x, lane = tid & 63, wid = tid >> 6;
    const int r0 = blockIdx.x * 4;
    const int fr = lane & 15, hi = lane >> 4, kq = hi * 8;

    int role, uw;
    if (wid < 2)      { role = 1; uw = wid * 32; }
    else if (wid < 6) { role = 2; uw = (wid - 2) * 32; }
    else              { role = 3; uw = (wid - 6) * 32; }

    // --- weight fragments (uniform shape across roles) ---
    // role 1: bregB = whh1 (K=64);               pairs with h1 frags
    // role 2: bregB = wih2 (K=64), bregA = whh2 (K=128); h1 & h2 frags
    // role 3: bregB = whh3 (K=64), bregA = wih3 (K=128); h3 & h2 frags
    short8 bregB[2][4][2];
    short8 bregA[2][4][4];
    #pragma unroll
    for (int ut = 0; ut < 2; ++ut)
        #pragma unroll
        for (int g = 0; g < 4; ++g) {
            const int uu = uw + ut * 16 + fr;
            const float *pB, *pA = nullptr;
            if (role == 1)      { pB = whh1 + (size_t)(g * 64 + uu) * 64; }
            else if (role == 2) { pB = wih2 + (size_t)(g * 128 + uu) * 64;
                                  pA = whh2 + (size_t)(g * 128 + uu) * 128; }
            else                { pB = whh3 + (size_t)(g * 64 + uu) * 64;
                                  pA = wih3 + (size_t)(g * 64 + uu) * 128; }
            #pragma unroll
            for (int ks = 0; ks < 2; ++ks) {
                short8 b;
                #pragma unroll
                for (int j = 0; j < 8; ++j)
                    b[j] = (short)f2bf(pB[ks * 32 + kq + j]);
                bregB[ut][g][ks] = b;
            }
            if (role >= 2) {
                #pragma unroll
                for (int ks = 0; ks < 4; ++ks) {
                    short8 b;
                    #pragma unroll
                    for (int j = 0; j < 8; ++j)
                        b[j] = (short)f2bf(pA[ks * 32 + kq + j]);
                    bregA[ut][g][ks] = b;
                }
            }
        }

    // --- bias table + zero h buffers ---
    for (int i = tid; i < 1024; i += 512) {
        float bv;
        if (i < 256)      bv = bih1[i] + bhh1[i];
        else if (i < 768) bv = bih2[i - 256] + bhh2[i - 256];
        else              bv = bih3[i - 768] + bhh3[i - 768];
        bsh[i] = bv;
        h1sh[0][i] = 0; h1sh[1][i] = 0;
        h3sh[0][i] = 0; h3sh[1][i] = 0;
    }
    for (int i = tid; i < 2048; i += 512) { h2sh[0][i] = 0; h2sh[1][i] = 0; }

    // stage xg1(t=0)
    if (tid < 128) {
        const int rw = tid >> 5, xc = (tid & 31) * 8;
        *(short8*)&xsh[0][rw * 256 + xc] =
            *(const short8*)(xg1 + ((size_t)(r0 + rw) * Tn) * 256 + xc);
    }

    float c[2] = {0.f, 0.f};
    __syncthreads();

    const int nSteps = Tn + 2;            // 66
    for (int s = 0; s < nSteps; ++s) {
        const int rb = s & 1, wb = rb ^ 1;

        // prefetch next xg1 tile into regs (hides under MFMA+cell)
        short8 xr;
        const bool doX = (tid < 128) && (s + 1 < Tn);
        if (doX) {
            const int rw = tid >> 5, xc = (tid & 31) * 8;
            xr = *(const short8*)(xg1 +
                 ((size_t)(r0 + rw) * Tn + (s + 1)) * 256 + xc);
        }

        // ---- MFMA phase (wave-uniform role/activity) ----
        const bool act = (role == 1) ? (s < Tn)
                       : (role == 2) ? (s >= 1 && s <= Tn)
                                     : (s >= 2 && s <= Tn + 1);
        if (act) {
            short8 a2r[2], a4r[4];
            const ushort_t* src2 = (role == 3) ? h3sh[rb] : h1sh[rb];
            #pragma unroll
            for (int ks = 0; ks < 2; ++ks) {
                const int k0 = ks * 32 + kq;
                a2r[ks] = *(const short8*)&src2[fr * 64 + (k0 ^ ((fr & 7) << 3))];
            }
            if (role >= 2) {
                #pragma unroll
                for (int ks = 0; ks < 4; ++ks) {
                    const int k0 = ks * 32 + kq;
                    a4r[ks] = *(const short8*)
                        &h2sh[rb][fr * 128 + (k0 ^ ((fr & 7) << 3))];
                }
            }
            const int sec = (role == 1) ? 0 : (role == 2) ? 256 : 768;
            const int Hl  = (role == 2) ? 128 : 64;
            #pragma unroll
            for (int ut = 0; ut < 2; ++ut)
                #pragma unroll
                for (int g = 0; g < 4; ++g) {
                    f32x4 acc = {};
                    #pragma unroll
                    for (int ks = 0; ks < 2; ++ks)
                        acc = __builtin_amdgcn_mfma_f32_16x16x32_bf16(
                            a2r[ks], bregB[ut][g][ks], acc, 0, 0, 0);
                    if (role >= 2) {
                        #pragma unroll
                        for (int ks = 0; ks < 4; ++ks)
                            acc = __builtin_amdgcn_mfma_f32_16x16x32_bf16(
                                a4r[ks], bregA[ut][g][ks], acc, 0, 0, 0);
                    }
                    if (hi == 0) {      // rows 0-3 are the real batch rows
                        const int col = sec + g * Hl + uw + ut * 16 + fr;
                        #pragma unroll
                        for (int j = 0; j < 4; ++j)
                            gsh[j][col] = acc[j];
                    }
                }
        }
        __syncthreads();                 // gates visible

        // ---- cell-update phase: all 512 threads, 2 items each ----
        #pragma unroll
        for (int i = 0; i < 2; ++i) {
            const int item = tid + i * 512;
            const int row = item >> 8, ug = item & 255;
            int u, Hl, sec, tt, lay;
            if (ug < 64)       { lay = 1; u = ug;       Hl = 64;  sec = 0;   tt = s; }
            else if (ug < 192) { lay = 2; u = ug - 64;  Hl = 128; sec = 256; tt = s - 1; }
            else               { lay = 3; u = ug - 192; Hl = 64;  sec = 768; tt = s - 2; }
            if (tt >= 0 && tt < Tn) {
                const int col0 = sec + u;
                float gi = gsh[row][col0]          + bsh[col0];
                float gf = gsh[row][col0 + Hl]     + bsh[col0 + Hl];
                float gg = gsh[row][col0 + 2 * Hl] + bsh[col0 + 2 * Hl];
                float go = gsh[row][col0 + 3 * Hl] + bsh[col0 + 3 * Hl];
                if (lay == 1) {
                    const ushort_t* xb = &xsh[s & 1][row * 256 + u];
                    gi += bf2f(xb[0]);   gf += bf2f(xb[64]);
                    gg += bf2f(xb[128]); go += bf2f(xb[192]);
                }
                const float iv = sigmoid_f(gi);
                const float fv = sigmoid_f(gf);
                const float gv = tanh_f(gg);
                const float ov = sigmoid_f(go);
                c[i] = fmaf(fv, c[i], iv * gv);
                const float h = ov * tanh_f(c[i]);
                ushort_t* hdst = (lay == 1) ? h1sh[wb]
                               : (lay == 2) ? h2sh[wb] : h3sh[wb];
                hdst[row * Hl + (u ^ (row << 3))] = f2bf(h);   // row<4
                if (lay == 3 && tt == Tn - 1)
                    hlast[(size_t)(r0 + row) * 64 + u] = h;
            }
        }

        // stage next xg tile
        if (doX) {
            const int rw = tid >> 5, xc = (tid & 31) * 8;
            *(short8*)&xsh[(s + 1) & 1][rw * 256 + xc] = xr;
        }
        __syncthreads();                 // h(wb), xg(s+1) visible
    }
}

// ---------------------------------------------------------------------------
// FC head: hlast[B,64] -> fc1 relu -> fc2 relu -> fc3 -> softmax
// ---------------------------------------------------------------------------
__global__ __launch_bounds__(256) void head_kernel(
    const float* __restrict__ hlast,
    const float* __restrict__ w1, const float* __restrict__ b1,
    const float* __restrict__ w2, const float* __restrict__ b2,
    const float* __restrict__ w3, const float* __restrict__ b3,
    float* __restrict__ out)
{
    __shared__ float W1[64][64];
    __shared__ float W2[32][64];
    __shared__ float W3[3][32];
    __shared__ float hin[16][64];
    __shared__ float a1[16][64];
    __shared__ float a2[16][32];
    __shared__ float lg[16][3];

    const int tid = threadIdx.x;
    const int r0 = blockIdx.x * 16;

    for (int i = tid; i < 64 * 64; i += 256) W1[i >> 6][i & 63] = w1[i];
    for (int i = tid; i < 32 * 64; i += 256) W2[i >> 6][i & 63] = w2[i];
    for (int i = tid; i < 3 * 32; i += 256) W3[i >> 5][i & 31] = w3[i];
    for (int i = tid; i < 16 * 64; i += 256) {
        int r = i >> 6, u = i & 63;
        hin[r][u] = hlast[(size_t)(r0 + r) * 64 + u];
    }
    __syncthreads();

    for (int i = tid; i < 16 * 64; i += 256) {
        int r = i >> 6, j = i & 63;
        float s = b1[j];
        #pragma unroll
        for (int k = 0; k < 64; ++k) s = fmaf(hin[r][k], W1[j][k], s);
        a1[r][j] = fmaxf(s, 0.f);
    }
    __syncthreads();

    for (int i = tid; i < 16 * 32; i += 256) {
        int r = i >> 5, j = i & 31;
        float s = b2[j];
        #pragma unroll
        for (int k = 0; k < 64; ++k) s = fmaf(a1[r][k], W2[j][k], s);
        a2[r][j] = fmaxf(s, 0.f);
    }
    __syncthreads();

    for (int i = tid; i < 16 * 3; i += 256) {
        int r = i / 3, j = i % 3;
        float s = b3[j];
        #pragma unroll
        for (int k = 0; k < 32; ++k) s = fmaf(a2[r][k], W3[j][k], s);
        lg[r][j] = s;
    }
    __syncthreads();

    if (tid < 16) {
        float l0 = lg[tid][0], l1 = lg[tid][1], l2 = lg[tid][2];
        float m = fmaxf(l0, fmaxf(l1, l2));
        float e0 = __expf(l0 - m), e1 = __expf(l1 - m), e2 = __expf(l2 - m);
        float inv = 1.0f / (e0 + e1 + e2);
        out[(size_t)(r0 + tid) * 3 + 0] = e0 * inv;
        out[(size_t)(r0 + tid) * 3 + 1] = e1 * inv;
        out[(size_t)(r0 + tid) * 3 + 2] = e2 * inv;
    }
}

// ---------------------------------------------------------------------------
extern "C" void kernel_launch(void* const* d_in, const int* in_sizes, int n_in,
                              void* d_out, int out_size, void* d_ws, size_t ws_size,
                              hipStream_t stream)
{
    const float* x    = (const float*)d_in[0];
    const float* wih1 = (const float*)d_in[1];
    const float* whh1 = (const float*)d_in[2];
    const float* bih1 = (const float*)d_in[3];
    const float* bhh1 = (const float*)d_in[4];
    const float* wih2 = (const float*)d_in[5];
    const float* whh2 = (const float*)d_in[6];
    const float* bih2 = (const float*)d_in[7];
    const float* bhh2 = (const float*)d_in[8];
    const float* wih3 = (const float*)d_in[9];
    const float* whh3 = (const float*)d_in[10];
    const float* bih3 = (const float*)d_in[11];
    const float* bhh3 = (const float*)d_in[12];
    const float* f1w  = (const float*)d_in[13];
    const float* f1b  = (const float*)d_in[14];
    const float* f2w  = (const float*)d_in[15];
    const float* f2b  = (const float*)d_in[16];
    const float* f3w  = (const float*)d_in[17];
    const float* f3b  = (const float*)d_in[18];
    float* outp = (float*)d_out;

    // workspace layout (~35 MB):
    //   bufA : 33,554,432 B  (bf16 [M,256]: xg1)
    //   hlast:    262,144 B  (fp32 [B,64])
    //   w1b  : bf16 w_ih1 (~0.9 MB)
    char* wsb = (char*)d_ws;
    size_t off = 0;
    ushort_t* bufA  = (ushort_t*)(wsb + off); off += 33554432;
    float*    hlast = (float*)(wsb + off);    off += 262144;
    ushort_t* w1b   = (ushort_t*)(wsb + off);

    const int T = T_SZ;

    convert_w1<<<208, 256, 0, stream>>>(wih1, w1b);

    // Layer 1 input GEMM (x read once; 4 blocks/CU)
    gemm_l1<<<M_SZ / 64, 256, 0, stream>>>(x, w1b, bufA);

    // All three LSTM layers, pipelined, one dispatch (256 blocks = all CUs)
    lstm3_pipe<<<B_SZ / 4, 512, 0, stream>>>(
        bufA, whh1, bih1, bhh1,
        wih2, whh2, bih2, bhh2,
        wih3, whh3, bih3, bhh3,
        hlast, T);

    // Head
    head_kernel<<<B_SZ / 16, 256, 0, stream>>>(
        hlast, f1w, f1b, f2w, f2b, f3w, f3b, outp);
}